// Round 15
// baseline (3204.611 us; speedup 1.0000x reference)
//
#include <hip/hip_runtime.h>
#include <hip/hip_bf16.h>
#include <math.h>

// ---------------- constants ----------------
#define B_   8
#define S_   1024
#define D_   768
#define H_   12
#define HD_  64
#define L_   12
#define F_   3072
#define NTOK 8192   // B_*S_

typedef __bf16 bf16x8 __attribute__((ext_vector_type(8)));
typedef float  f32x4  __attribute__((ext_vector_type(4)));
typedef unsigned short u16;

static __device__ __forceinline__ unsigned short f2bf_bits(float f) {
    __hip_bfloat16 h = __float2bfloat16(f);
    return __builtin_bit_cast(unsigned short, h);
}
static __device__ __forceinline__ float bf2f(unsigned short u) {
    unsigned int t = ((unsigned int)u) << 16;
    return __builtin_bit_cast(float, t);
}
static __device__ __forceinline__ void gload16(const void* g, void* l) {
    __builtin_amdgcn_global_load_lds(
        (__attribute__((address_space(1))) void*)g,
        (__attribute__((address_space(3))) void*)l, 16, 0, 0);
}

// ---------------- fused: weight prep (blocks 0..1727) + LN1 (blocks 1728..3775) --------
__global__ __launch_bounds__(256)
void prep_ln_kernel(const float* __restrict__ Wq, const float* __restrict__ Wk,
                    const float* __restrict__ Wv, const float* __restrict__ Wo,
                    const float* __restrict__ W1, const float* __restrict__ W2,
                    int l, __hip_bfloat16* __restrict__ wbuf,
                    const float* __restrict__ xin, const float* __restrict__ gam,
                    const float* __restrict__ bet, __hip_bfloat16* __restrict__ xnout)
{
    __shared__ u16 T[64][68];
    if (blockIdx.x >= 1728) {
        // ---------------- LN path ----------------
        const int row  = (blockIdx.x - 1728)*4 + (threadIdx.x >> 6);
        const int lane = threadIdx.x & 63;
        const float* xr = xin + (size_t)row * D_;
        float v[12]; float s1 = 0.f, s2 = 0.f;
#pragma unroll
        for (int c = 0; c < 3; ++c) {
            float4 t = *(const float4*)(xr + c*256 + lane*4);
            v[c*4+0]=t.x; v[c*4+1]=t.y; v[c*4+2]=t.z; v[c*4+3]=t.w;
            s1 += t.x+t.y+t.z+t.w;
            s2 += t.x*t.x + t.y*t.y + t.z*t.z + t.w*t.w;
        }
#pragma unroll
        for (int off = 32; off > 0; off >>= 1) { s1 += __shfl_xor(s1, off); s2 += __shfl_xor(s2, off); }
        const float mean = s1 * (1.f/768.f);
        const float rstd = rsqrtf(s2*(1.f/768.f) - mean*mean + 1e-5f);
        unsigned short* op = (unsigned short*)xnout + (size_t)row * D_;
#pragma unroll
        for (int c = 0; c < 3; ++c) {
            const int base = c*256 + lane*4;
            float4 g = *(const float4*)(gam + base);
            float4 bb = *(const float4*)(bet + base);
            ushort4 pk;
            pk.x = f2bf_bits((v[c*4+0]-mean)*rstd*g.x + bb.x);
            pk.y = f2bf_bits((v[c*4+1]-mean)*rstd*g.y + bb.y);
            pk.z = f2bf_bits((v[c*4+2]-mean)*rstd*g.z + bb.z);
            pk.w = f2bf_bits((v[c*4+3]-mean)*rstd*g.w + bb.w);
            *(ushort4*)(op + base) = pk;
        }
        return;
    }
    // ---------------- prep path ----------------
    const int id = blockIdx.x;   // 0..1727
    const float* src; __hip_bfloat16* dst;
    int R, C, r0, c0;
    if (id < 432) {
        int dtile = id % 12, t = id / 12;
        int which = t / 12, h = t % 12;
        src = (which == 0 ? Wq : which == 1 ? Wk : Wv) + (size_t)(l*12 + h) * 768 * 64;
        dst = wbuf + (size_t)(which*768 + h*64) * 768;
        R = 768; C = 64; r0 = dtile * 64; c0 = 0;
    } else if (id < 576) {
        int t = id - 432;
        src = Wo + (size_t)l * 768 * 768;
        dst = wbuf + 1769472;
        R = 768; C = 768; r0 = (t / 12) * 64; c0 = (t % 12) * 64;
    } else if (id < 1152) {
        int t = id - 576;
        src = W1 + (size_t)l * 768 * 3072;
        dst = wbuf + 2359296;
        R = 768; C = 3072; r0 = (t % 12) * 64; c0 = (t / 12) * 64;
    } else {
        int t = id - 1152;
        src = W2 + (size_t)l * 3072 * 768;
        dst = wbuf + 4718592;
        R = 3072; C = 768; r0 = (t / 12) * 64; c0 = (t % 12) * 64;
    }
    const int t = threadIdx.x;
    const int row = t >> 2, part = t & 3;
#pragma unroll
    for (int j = 0; j < 4; ++j) {
        const int c4 = (part + j*4) * 4;
        float4 v = *(const float4*)(src + (size_t)(r0 + row) * C + c0 + c4);
        T[c4+0][row] = f2bf_bits(v.x);
        T[c4+1][row] = f2bf_bits(v.y);
        T[c4+2][row] = f2bf_bits(v.z);
        T[c4+3][row] = f2bf_bits(v.w);
    }
    __syncthreads();
    const int c = t >> 2;
    u16* drow = (u16*)dst + (size_t)(c0 + c) * R + r0;
#pragma unroll
    for (int j = 0; j < 4; ++j) {
        const int r4 = (part + j*4) * 4;
        ushort4 pk = *(const ushort4*)&T[c][r4];
        *(ushort4*)(drow + r4) = pk;
    }
}

__global__ __launch_bounds__(256)
void prep_bqkv_kernel(const float* __restrict__ bq, const float* __restrict__ bk,
                      const float* __restrict__ bv, float* __restrict__ bqkv)
{
    int i = blockIdx.x * 256 + threadIdx.x;   // < 12*2304
    int l = i / 2304, c = i % 2304;
    int which = c / 768, hk = c % 768;
    const float* src = which == 0 ? bq : which == 1 ? bk : bv;
    bqkv[i] = src[l*768 + hk];
}

// ---------------- embedding + LN -> x (fp32) ----------------
__global__ __launch_bounds__(256)
void embed_ln_kernel(const int* __restrict__ tokens, const float* __restrict__ tok_emb,
                     const float* __restrict__ pos_emb, const float* __restrict__ gam,
                     const float* __restrict__ bet, float* __restrict__ x)
{
    const int row  = blockIdx.x*4 + (threadIdx.x >> 6);
    const int lane = threadIdx.x & 63;
    const int s    = row & (S_-1);
    const int tok  = tokens[row];
    const float* te = tok_emb + (size_t)tok * D_;
    const float* pe = pos_emb + (size_t)s   * D_;
    float v[12]; float s1 = 0.f, s2 = 0.f;
#pragma unroll
    for (int c = 0; c < 3; ++c) {
        const int base = c*256 + lane*4;
        float4 a = *(const float4*)(te + base);
        float4 p = *(const float4*)(pe + base);
        float t0 = a.x+p.x, t1 = a.y+p.y, t2 = a.z+p.z, t3 = a.w+p.w;
        v[c*4+0]=t0; v[c*4+1]=t1; v[c*4+2]=t2; v[c*4+3]=t3;
        s1 += t0+t1+t2+t3;
        s2 += t0*t0 + t1*t1 + t2*t2 + t3*t3;
    }
#pragma unroll
    for (int off = 32; off > 0; off >>= 1) { s1 += __shfl_xor(s1, off); s2 += __shfl_xor(s2, off); }
    const float mean = s1 * (1.f/768.f);
    const float rstd = rsqrtf(s2*(1.f/768.f) - mean*mean + 1e-5f);
    float* xr = x + (size_t)row * D_;
#pragma unroll
    for (int c = 0; c < 3; ++c) {
        const int base = c*256 + lane*4;
        float4 g = *(const float4*)(gam + base);
        float4 bb = *(const float4*)(bet + base);
        float4 o;
        o.x = (v[c*4+0]-mean)*rstd*g.x + bb.x;
        o.y = (v[c*4+1]-mean)*rstd*g.y + bb.y;
        o.z = (v[c*4+2]-mean)*rstd*g.z + bb.z;
        o.w = (v[c*4+3]-mean)*rstd*g.w + bb.w;
        *(float4*)(xr + base) = o;
    }
}

// ---------------- LN: x (fp32) -> xn (bf16) ----------------
__global__ __launch_bounds__(256)
void ln_kernel(const float* __restrict__ xin, const float* __restrict__ gam,
               const float* __restrict__ bet, __hip_bfloat16* __restrict__ out)
{
    const int row  = blockIdx.x*4 + (threadIdx.x >> 6);
    const int lane = threadIdx.x & 63;
    const float* xr = xin + (size_t)row * D_;
    float v[12]; float s1 = 0.f, s2 = 0.f;
#pragma unroll
    for (int c = 0; c < 3; ++c) {
        float4 t = *(const float4*)(xr + c*256 + lane*4);
        v[c*4+0]=t.x; v[c*4+1]=t.y; v[c*4+2]=t.z; v[c*4+3]=t.w;
        s1 += t.x+t.y+t.z+t.w;
        s2 += t.x*t.x + t.y*t.y + t.z*t.z + t.w*t.w;
    }
#pragma unroll
    for (int off = 32; off > 0; off >>= 1) { s1 += __shfl_xor(s1, off); s2 += __shfl_xor(s2, off); }
    const float mean = s1 * (1.f/768.f);
    const float rstd = rsqrtf(s2*(1.f/768.f) - mean*mean + 1e-5f);
    unsigned short* op = (unsigned short*)out + (size_t)row * D_;
#pragma unroll
    for (int c = 0; c < 3; ++c) {
        const int base = c*256 + lane*4;
        float4 g = *(const float4*)(gam + base);
        float4 bb = *(const float4*)(bet + base);
        ushort4 pk;
        pk.x = f2bf_bits((v[c*4+0]-mean)*rstd*g.x + bb.x);
        pk.y = f2bf_bits((v[c*4+1]-mean)*rstd*g.y + bb.y);
        pk.z = f2bf_bits((v[c*4+2]-mean)*rstd*g.z + bb.z);
        pk.w = f2bf_bits((v[c*4+3]-mean)*rstd*g.w + bb.w);
        *(ushort4*)(op + base) = pk;
    }
}

// ---------------- GEMM 256x128, 8 waves (64x64 each), BK=32, counted-vmcnt pipeline ----
template<int EPI>
__global__ __launch_bounds__(512, 2)
void gemm256_kernel(const __hip_bfloat16* __restrict__ A,
                    const __hip_bfloat16* __restrict__ Bt,
                    const float* __restrict__ bias,
                    __hip_bfloat16* __restrict__ outb,
                    __hip_bfloat16* __restrict__ outv,
                    int N, int K, int nTiles)
{
    __shared__ __align__(16) char smem[49152];
    char* const As0 = smem;            // 16 KB: A [256][32] bf16, swizzled
    char* const As1 = smem + 16384;
    char* const Bs0 = smem + 32768;    // 8 KB: B [128][32]
    char* const Bs1 = smem + 40960;

    const int tid  = threadIdx.x;
    const int lane = tid & 63;
    const int wid  = tid >> 6;          // 0..7

    const int nwg   = gridDim.x;
    const int chunk = nwg >> 3;
    const int bid   = blockIdx.x;
    const int swz   = (bid & 7) * chunk + (bid >> 3);
    const int m0 = (swz / nTiles) * 256;
    const int n0 = (swz % nTiles) * 128;

    const int l4 = lane >> 2;                              // 0..15
    const int sswz = ((lane & 3) ^ ((l4 >> 1) & 3)) * 8;   // source col (elements)
    const __hip_bfloat16* aSrc = A  + (size_t)(m0 + wid*16 + l4) * K + sswz;
    const __hip_bfloat16* bSrc = Bt + (size_t)(n0 + wid*16 + l4) * K + sswz;
    const int sOff = wid*1024 + lane*16;

    f32x4 acc[4][4] = {};
    const int wm = wid >> 1, wn = wid & 1;   // 4 m-waves x 2 n-waves
    const int cl = lane & 15, hi = lane >> 4;

    int aoff[4], boff[4];
#pragma unroll
    for (int m = 0; m < 4; ++m) {
        const int row = wm*64 + m*16 + cl;                 // 0..255
        aoff[m] = row*64 + ((hi ^ ((row >> 1) & 3)) << 4);
    }
#pragma unroll
    for (int n = 0; n < 4; ++n) {
        const int row = wn*64 + n*16 + cl;                 // 0..127
        boff[n] = row*64 + ((hi ^ ((row >> 1) & 3)) << 4);
    }

    auto STAGE = [&](char* aBuf, char* bBuf, int kt) {
        gload16(aSrc + kt,                  aBuf + sOff);
        gload16(aSrc + kt + (size_t)128*K,  aBuf + 8192 + sOff);
        gload16(bSrc + kt,                  bBuf + sOff);
    };

    const int NT = K >> 5;   // K/32
    STAGE(As0, Bs0, 0);
    STAGE(As1, Bs1, 32);

    for (int t = 0; t < NT; ++t) {
        if (t < NT - 1) asm volatile("s_waitcnt vmcnt(3)" ::: "memory");
        else            asm volatile("s_waitcnt vmcnt(0)" ::: "memory");
        __builtin_amdgcn_s_barrier();

        char* const ac = (t & 1) ? As1 : As0;
        char* const bc = (t & 1) ? Bs1 : Bs0;
        bf16x8 af[4], bfr[4];
#pragma unroll
        for (int m = 0; m < 4; ++m) af[m]  = *(const bf16x8*)(ac + aoff[m]);
#pragma unroll
        for (int n = 0; n < 4; ++n) bfr[n] = *(const bf16x8*)(bc + boff[n]);
        asm volatile("s_waitcnt lgkmcnt(0)" ::: "memory");
        __builtin_amdgcn_sched_barrier(0);
        __builtin_amdgcn_s_barrier();

        if (t + 2 < NT) STAGE(ac, bc, (t + 2) << 5);   // overwrite just-consumed buffer

        __builtin_amdgcn_s_setprio(1);
#pragma unroll
        for (int m = 0; m < 4; ++m)
#pragma unroll
            for (int n = 0; n < 4; ++n)
                acc[m][n] = __builtin_amdgcn_mfma_f32_16x16x32_bf16(af[m], bfr[n], acc[m][n], 0, 0, 0);
        __builtin_amdgcn_s_setprio(0);
    }

    const bool vpath = (EPI == 0) && (n0 >= 1536);

    if (!vpath) {
        // bf16 repack through LDS in two 128-row halves -> coalesced float4 stores
        const int strideN = (EPI == 0) ? 1536 : N;
#pragma unroll
        for (int half = 0; half < 2; ++half) {
            __syncthreads();
            if ((wm >> 1) == half) {
#pragma unroll
                for (int n = 0; n < 4; ++n) {
                    const int col2 = wn*64 + n*16 + cl;
                    const float bv = bias[n0 + col2];
#pragma unroll
                    for (int m = 0; m < 4; ++m) {
#pragma unroll
                        for (int i = 0; i < 4; ++i) {
                            const int row = (wm & 1)*64 + m*16 + hi*4 + i;  // 0..127
                            float v = acc[m][n][i] + bv;
                            if constexpr (EPI == 1) {
                                const float y = 0.7978845608f * (v + 0.044715f*v*v*v);
                                const float e = __expf(-2.0f * fabsf(y));
                                const float th = (1.0f - e) / (1.0f + e);
                                v = 0.5f * v * (1.0f + copysignf(th, y));
                            }
                            *(u16*)(smem + row*256 + ((((col2 >> 3) ^ (row & 15))) << 4)
                                         + ((col2 & 7) << 1)) = f2bf_bits(v);
                        }
                    }
                }
            }
            __syncthreads();
            const int r = tid >> 2;        // 0..127
            const int part = tid & 3;
            char* dst = (char*)outb + ((size_t)(m0 + half*128 + r) * strideN + n0) * 2;
#pragma unroll
            for (int j = 0; j < 4; ++j) {
                const int ch = part + j*4;               // 0..15
                float4 vv = *(const float4*)(smem + r*256 + ((ch ^ (r & 15)) << 4));
                *(float4*)(dst + ch*16) = vv;
            }
        }
    } else {
        // V -> V^T via LDS transpose, two 128-row halves
        const int hdbase = n0 - 1536;
        const int bb = m0 >> 10;
#pragma unroll
        for (int half = 0; half < 2; ++half) {
            __syncthreads();
            if ((wm >> 1) == half) {
#pragma unroll
                for (int n = 0; n < 4; ++n) {
                    const int hdl = wn*64 + n*16 + cl;     // 0..127
                    const float bv = bias[n0 + hdl];
#pragma unroll
                    for (int m = 0; m < 4; ++m) {
                        const int sl = (wm & 1)*64 + m*16 + hi*4;   // s-local 0..127
                        ushort4 pk;
                        pk.x = f2bf_bits(acc[m][n][0] + bv);
                        pk.y = f2bf_bits(acc[m][n][1] + bv);
                        pk.z = f2bf_bits(acc[m][n][2] + bv);
                        pk.w = f2bf_bits(acc[m][n][3] + bv);
                        *(ushort4*)(smem + hdl*256 + ((((sl >> 3) ^ (hdl & 15))) << 4)
                                         + (sl & 7)*2) = pk;
                    }
                }
            }
            __syncthreads();
            const int hdl2 = tid >> 2;        // 0..127
            const int q4   = tid & 3;
            u16* dst = (u16*)outv + ((size_t)(bb*768) + hdbase + hdl2)*1024
                                  + (m0 & 1023) + half*128;
#pragma unroll
            for (int j = 0; j < 4; ++j) {
                const int ch = q4*4 + j;                  // 0..15
                const int slot = ch ^ (hdl2 & 15);
                *(float4*)((char*)dst + ch*16) = *(const float4*)(smem + hdl2*256 + (slot << 4));
            }
        }
    }
}

// ---------------- GEMM 64x128, 4 waves, counted-vmcnt dbuf: outf += A*Bt^T + bias ----
__global__ __launch_bounds__(256)
void gemm_res_kernel(const __hip_bfloat16* __restrict__ A,
                     const __hip_bfloat16* __restrict__ Bt,
                     const float* __restrict__ bias,
                     float* __restrict__ outf,
                     int N, int K, int nTiles)
{
    __shared__ __align__(16) char smem[49152];
    char* const As0 = smem;            // 8 KB [64][64]
    char* const As1 = smem + 8192;
    char* const Bs0 = smem + 16384;    // 16 KB [128][64]
    char* const Bs1 = smem + 32768;

    const int tid  = threadIdx.x;
    const int lane = tid & 63;
    const int wid  = tid >> 6;

    const int nwg   = gridDim.x;
    const int chunk = nwg >> 3;
    const int bid   = blockIdx.x;
    const int swz   = (bid & 7) * chunk + (bid >> 3);
    const int m0 = (swz / nTiles) * 64;
    const int n0 = (swz % nTiles) * 128;

    const int lrow = lane >> 3;                 // 0..7
    const int scol = ((lane & 7) ^ lrow) * 8;   // swizzled source col
    const __hip_bfloat16* aSrc = A  + (size_t)(m0 + wid*16 + lrow) * K + scol;
    const __hip_bfloat16* bSrc = Bt + (size_t)(n0 + wid*32 + lrow) * K + scol;
    const int aOff = wid*2048 + lane*16;
    const int bOff = wid*4096 + lane*16;

    f32x4 acc[2][4] = {};
    const int wm = wid >> 1, wn = wid & 1;
    const int cl = lane & 15, hi = lane >> 4;

    auto STAGE = [&](char* aBuf, char* bBuf, int kt) {
#pragma unroll
        for (int i = 0; i < 2; ++i)
            gload16(aSrc + kt + (size_t)i*8*K, aBuf + aOff + i*1024);
#pragma unroll
        for (int i = 0; i < 4; ++i)
            gload16(bSrc + kt + (size_t)i*8*K, bBuf + bOff + i*1024);
    };

    const int NT = K >> 6;   // K/64
    STAGE(As0, Bs0, 0);
    STAGE(As1, Bs1, 64);

    for (int t = 0; t < NT; ++t) {
        if (t < NT - 1) asm volatile("s_waitcnt vmcnt(6)" ::: "memory");
        else            asm volatile("s_waitcnt vmcnt(0)" ::: "memory");
        __builtin_amdgcn_s_barrier();

        char* const ac = (t & 1) ? As1 : As0;
        char* const bc = (t & 1) ? Bs1 : Bs0;
        bf16x8 af[2][2], bfr[2][4];
#pragma unroll
        for (int kk = 0; kk < 2; ++kk) {
#pragma unroll
            for (int m = 0; m < 2; ++m) {
                const int row  = wm*32 + m*16 + cl;
                const int slot = ((kk<<2) + hi) ^ (row & 7);
                af[kk][m] = *(const bf16x8*)(ac + row*128 + slot*16);
            }
#pragma unroll
            for (int n = 0; n < 4; ++n) {
                const int row  = wn*64 + n*16 + cl;
                const int slot = ((kk<<2) + hi) ^ (row & 7);
                bfr[kk][n] = *(const bf16x8*)(bc + row*128 + slot*16);
            }
        }
        asm volatile("s_waitcnt lgkmcnt(0)" ::: "memory");
        __builtin_amdgcn_sched_barrier(0);
        __builtin_amdgcn_s_barrier();

        if (t + 2 < NT) STAGE(ac, bc, (t + 2) << 6);

        __builtin_amdgcn_s_setprio(1);
#pragma unroll
        for (int kk = 0; kk < 2; ++kk)
#pragma unroll
            for (int m = 0; m < 2; ++m)
#pragma unroll
                for (int n = 0; n < 4; ++n)
                    acc[m][n] = __builtin_amdgcn_mfma_f32_16x16x32_bf16(af[kk][m], bfr[kk][n], acc[m][n], 0, 0, 0);
        __builtin_amdgcn_s_setprio(0);
    }

    __syncthreads();   // staging LDS dead; reuse for fp32 repack

#pragma unroll
    for (int n = 0; n < 4; ++n) {
        const int col = wn*64 + n*16 + cl;
        const float bv = bias[n0 + col];
#pragma unroll
        for (int m = 0; m < 2; ++m) {
#pragma unroll
            for (int i = 0; i < 4; ++i) {
                const int row = wm*32 + m*16 + hi*4 + i;
                *(float*)(smem + row*512 + ((((col >> 2) ^ (row & 31))) << 4)
                               + ((col & 3) << 2)) = acc[m][n][i] + bv;
            }
        }
    }
    __syncthreads();
    const int r = tid >> 2;
    const int part = tid & 3;
    float* drow = outf + (size_t)(m0 + r) * N + n0;
#pragma unroll
    for (int j = 0; j < 8; ++j) {
        const int ch = part + j*4;
        f32x4 vv = *(const f32x4*)(smem + r*512 + ((ch ^ (r & 31)) << 4));
        float* dp = drow + ch*4;
        f32x4 g = *(const f32x4*)dp;
        g += vv;
        *(f32x4*)dp = g;
    }
}

// ---------------- flash attention, MFMA bf16 ----------------
// 4 waves x 32 q-rows (2 q-groups of 16) = 128 q-rows/block; halves per-q-row
// LDS K/V read duplication vs the 8-wave/16-row layout. Inline PV (R13 structure).
__global__ __launch_bounds__(256)
void attn_kernel(const __hip_bfloat16* __restrict__ qkb, const __hip_bfloat16* __restrict__ vtb,
                 __hip_bfloat16* __restrict__ attno)
{
    __shared__ __align__(16) char Ks[2][8192];  // [t 64][d 64] bf16, slot^=(t&7)
    __shared__ __align__(16) char Vs[2][8192];  // [d 64][t 64] bf16, slot^=(d&7)
    __shared__ __align__(16) char Ps[16384];    // per-wave P: [q 32][t 64], slot^=(q&7)

    const u16* qk = (const u16*)qkb;
    const u16* vt = (const u16*)vtb;
    const int nwg = gridDim.x, bid = blockIdx.x, chunk = nwg >> 3;
    const int swz = (bid & 7) * chunk + (bid >> 3);
    const int bh = swz >> 3, qb = swz & 7;
    const int b = bh / H_, h = bh % H_;
    const int tid = threadIdx.x;
    const int lane = tid & 63, wid = tid >> 6;   // wid 0..3
    const int cl = lane & 15, hi = lane >> 4;
    const size_t browq = (size_t)(b*S_ + qb*128);

    // Q fragments for 2 q-groups (rows wid*32 + g*16 + cl), pre-scaled by log2(e)/8
    bf16x8 qf[2][2];
#pragma unroll
    for (int g = 0; g < 2; ++g) {
        const float qs = 0.1803368801f;
        const u16* qp = qk + (browq + wid*32 + g*16 + cl)*1536 + h*64;
        u16 qt[16];
#pragma unroll
        for (int j = 0; j < 8; ++j) {
            qt[j]     = f2bf_bits(bf2f(qp[hi*8 + j]) * qs);
            qt[8 + j] = f2bf_bits(bf2f(qp[32 + hi*8 + j]) * qs);
        }
        qf[g][0] = *(const bf16x8*)&qt[0];
        qf[g][1] = *(const bf16x8*)&qt[8];
    }

    // staging: wave covers 16 rows (2 gload rounds of 8)
    const int lrow = lane >> 3;                  // 0..7
    const int scol = ((lane & 7) ^ lrow) * 8;    // swizzled source col
    const u16* kbase = qk + ((size_t)b*S_ + wid*16 + lrow)*1536 + 768 + h*64 + scol;
    const u16* vbase = vt + (((size_t)(b*H_ + h))*64 + wid*16 + lrow)*1024 + scol;
    const int ldst = wid*2048 + lane*16;

    char* pbase = Ps + wid*4096;

    f32x4 acc_o[2][4] = {};
    float m_run = -1e30f;                        // log2 domain
    float l_part[2][4] = {};

    {
        gload16(kbase,                  Ks[0] + ldst);
        gload16(kbase + (size_t)8*1536, Ks[0] + ldst + 1024);
        gload16(vbase,                  Vs[0] + ldst);
        gload16(vbase + 8*1024,         Vs[0] + ldst + 1024);
    }

    for (int t = 0; t < 16; ++t) {
        __syncthreads();
        if (t < 15) {
            const int nb = (t+1) & 1;
            const u16* kn = kbase + (size_t)(t+1)*64*1536;
            const u16* vn = vbase + (t+1)*64;
            gload16(kn,                  Ks[nb] + ldst);
            gload16(kn + (size_t)8*1536, Ks[nb] + ldst + 1024);
            gload16(vn,                  Vs[nb] + ldst);
            gload16(vn + 8*1024,         Vs[nb] + ldst + 1024);
        }
        const char* ks = Ks[t & 1];
        const char* vs = Vs[t & 1];

        // QK(t): kf read once, used by both q-groups
        f32x4 sc[2][4] = {};
#pragma unroll
        for (int kk = 0; kk < 2; ++kk) {
            bf16x8 kf[4];
#pragma unroll
            for (int n = 0; n < 4; ++n) {
                const int row = n*16 + cl;
                kf[n] = *(const bf16x8*)(ks + row*128 + (((kk*4 + hi) ^ (cl & 7)) << 4));
            }
#pragma unroll
            for (int g = 0; g < 2; ++g)
#pragma unroll
                for (int n = 0; n < 4; ++n)
                    sc[g][n] = __builtin_amdgcn_mfma_f32_16x16x32_bf16(qf[g][kk], kf[n], sc[g][n], 0, 0, 0);
        }

        // softmax (log2 domain, scale folded into Q); shared running max
        float gmax;
        {
            float a0 = fmaxf(fmaxf(sc[0][0][0], sc[0][0][1]), fmaxf(sc[0][0][2], sc[0][0][3]));
#pragma unroll
            for (int g = 0; g < 2; ++g)
#pragma unroll
                for (int n = 0; n < 4; ++n) {
                    if (g == 0 && n == 0) continue;
                    a0 = fmaxf(a0, fmaxf(fmaxf(sc[g][n][0], sc[g][n][1]), fmaxf(sc[g][n][2], sc[g][n][3])));
                }
            gmax = a0;
        }
        gmax = fmaxf(gmax, __shfl_xor(gmax, 1));
        gmax = fmaxf(gmax, __shfl_xor(gmax, 2));
        gmax = fmaxf(gmax, __shfl_xor(gmax, 4));
        gmax = fmaxf(gmax, __shfl_xor(gmax, 8));
        if (gmax > m_run + 5.7707801636f) {      // 4*log2(e): P bounded by e^4
            const float corr = exp2f(m_run - gmax);
            m_run = gmax;
#pragma unroll
            for (int g = 0; g < 2; ++g)
#pragma unroll
                for (int i = 0; i < 4; ++i) l_part[g][i] *= corr;
#pragma unroll
            for (int g = 0; g < 2; ++g)
#pragma unroll
                for (int nd = 0; nd < 4; ++nd)
#pragma unroll
                    for (int i = 0; i < 4; ++i)
                        acc_o[g][nd][i] *= corr;
        }

        // P -> LDS (per-wave region, [q 32][t 64])
#pragma unroll
        for (int g = 0; g < 2; ++g) {
#pragma unroll
            for (int n = 0; n < 4; ++n) {
#pragma unroll
                for (int i = 0; i < 4; ++i) {
                    const float e = exp2f(sc[g][n][i] - m_run);
                    l_part[g][i] += e;
                    const int q = g*16 + hi*4 + i;
                    const int slot = (n*2 + (cl >> 3)) ^ (q & 7);
                    *(u16*)(pbase + q*128 + slot*16 + (cl & 7)*2) = f2bf_bits(e);
                }
            }
        }

        asm volatile("s_waitcnt lgkmcnt(0)" ::: "memory");
        __builtin_amdgcn_sched_barrier(0);

        // PV: vf read once per kk, used by both q-groups
#pragma unroll
        for (int kk = 0; kk < 2; ++kk) {
            bf16x8 pf[2];
#pragma unroll
            for (int g = 0; g < 2; ++g) {
                const int qrow = g*16 + cl;
                pf[g] = *(const bf16x8*)(pbase + qrow*128 + (((kk*4 + hi) ^ (cl & 7)) << 4));
            }
            bf16x8 vf[4];
#pragma unroll
            for (int nd = 0; nd < 4; ++nd) {
                const int d = nd*16 + cl;
                vf[nd] = *(const bf16x8*)(vs + d*128 + (((kk*4 + hi) ^ (d & 7)) << 4));
            }
#pragma unroll
            for (int g = 0; g < 2; ++g)
#pragma unroll
                for (int nd = 0; nd < 4; ++nd)
                    acc_o[g][nd] = __builtin_amdgcn_mfma_f32_16x16x32_bf16(pf[g], vf[nd], acc_o[g][nd], 0, 0, 0);
        }
    }

    u16* op = (u16*)attno;
#pragma unroll
    for (int g = 0; g < 2; ++g) {
#pragma unroll
        for (int i = 0; i < 4; ++i) {
            float l = l_part[g][i];
            l += __shfl_xor(l, 1);
            l += __shfl_xor(l, 2);
            l += __shfl_xor(l, 4);
            l += __shfl_xor(l, 8);
            const float inv = 1.f / l;
            const size_t row = browq + wid*32 + g*16 + hi*4 + i;
#pragma unroll
            for (int nd = 0; nd < 4; ++nd)
                op[row*768 + h*64 + nd*16 + cl] = f2bf_bits(acc_o[g][nd][i] * inv);
        }
    }
}

// ---------------- classifier ----------------
__global__ __launch_bounds__(256)
void cls_kernel(const float* __restrict__ x, const float* __restrict__ Wc,
                const float* __restrict__ bc, float* __restrict__ out)
{
    const int b = blockIdx.x;
    const float* xr = x + (size_t)b * S_ * D_;
    float a0 = 0.f, a1 = 0.f;
    for (int d = threadIdx.x; d < 768; d += 256) {
        float xv = xr[d];
        a0 += xv * Wc[d*2+0];
        a1 += xv * Wc[d*2+1];
    }
#pragma unroll
    for (int off = 32; off > 0; off >>= 1) { a0 += __shfl_xor(a0, off); a1 += __shfl_xor(a1, off); }
    __shared__ float r0[4], r1[4];
    const int w = threadIdx.x >> 6;
    if ((threadIdx.x & 63) == 0) { r0[w] = a0; r1[w] = a1; }
    __syncthreads();
    if (threadIdx.x == 0) {
        out[b*2+0] = r0[0]+r0[1]+r0[2]+r0[3] + bc[0];
        out[b*2+1] = r1[0]+r1[1]+r1[2]+r1[3] + bc[1];
    }
}

// ---------------- launch ----------------
extern "C" void kernel_launch(void* const* d_in, const int* in_sizes, int n_in,
                              void* d_out, int out_size, void* d_ws, size_t ws_size,
                              hipStream_t stream)
{
    const int*   tokens  = (const int*)  d_in[0];
    const float* tok_emb = (const float*)d_in[1];
    const float* pos_emb = (const float*)d_in[2];
    const float* e_s     = (const float*)d_in[3];
    const float* e_b     = (const float*)d_in[4];
    const float* Wq      = (const float*)d_in[5];
    const float* bq      = (const float*)d_in[6];
    const float* Wk      = (const float*)d_in[7];
    const float* bk      = (const float*)d_in[8];
    const float* Wv      = (const float*)d_in[9];
    const float* bv      = (const float*)d_in[10];
    const float* Wo      = (const float*)d_in[11];
    const float* bo      = (const float*)d_in[12];
    const float* l1s     = (const float*)d_in[13];
    const float* l1b     = (const float*)d_in[14];
    const float* l2s     = (const float*)d_in[15];
    const float* l2b     = (const float*)d_in[16];
    const float* W1      = (const float*)d_in[17];
    const float* b1      = (const float*)d_in[18];
    const float* W2      = (const float*)d_in[19];
    const float* b2      = (const float*)d_in[20];
    const float* Wc      = (const float*)d_in[21];
    const float* bc      = (const float*)d_in[22];
    (void)in_sizes; (void)n_in; (void)out_size;

    if (ws_size < 102346752) return;   // need ~102.4 MB

    char* ws = (char*)d_ws;
    __hip_bfloat16* wbuf = (__hip_bfloat16*)(ws + 0);          // 14,155,776 B
    float*          bqkv = (float*)(ws + 14155776);            //    110,592 B
    float*          x    = (float*)(ws + 14266368);            // 25,165,824 B
    __hip_bfloat16* xn   = (__hip_bfloat16*)(ws + 39432192);   // 12,582,912 B
    __hip_bfloat16* qk   = (__hip_bfloat16*)(ws + 52015104);   // 25,165,824 B [8192][1536]
    __hip_bfloat16* vT   = (__hip_bfloat16*)(ws + 77180928);   // 12,582,912 B [b*768+hd][1024]
    __hip_bfloat16* att  = (__hip_bfloat16*)(ws + 89763840);   // 12,582,912 B (end 102,346,752)
    __hip_bfloat16* hbuf = qk;                                 // aliases qk+vT+att (50,331,648 B)

    __hip_bfloat16* wqkv_t = wbuf;
    __hip_bfloat16* wo_t   = wbuf + 1769472;
    __hip_bfloat16* w1_t   = wbuf + 2359296;
    __hip_bfloat16* w2_t   = wbuf + 4718592;

    prep_bqkv_kernel<<<108, 256, 0, stream>>>(bq, bk, bv, bqkv);
    embed_ln_kernel<<<2048, 256, 0, stream>>>(tokens, tok_emb, pos_emb, e_s, e_b, x);

    for (int l = 0; l < L_; ++l) {
        prep_ln_kernel<<<3776, 256, 0, stream>>>(Wq, Wk, Wv, Wo, W1, W2, l, wbuf,
                                                 x, l1s + l*768, l1b + l*768, xn);
        gemm256_kernel<0><<<576, 512, 0, stream>>>(xn, wqkv_t, bqkv + l*2304, qk, vT, 2304, 768, 18);
        attn_kernel<<<768, 256, 0, stream>>>(qk, vT, att);
        gemm_res_kernel<<<768, 256, 0, stream>>>(att, wo_t, bo + l*768, x, 768, 768, 6);
        ln_kernel<<<2048, 256, 0, stream>>>(x, l2s + l*768, l2b + l*768, xn);
        gemm256_kernel<1><<<768, 512, 0, stream>>>(xn, w1_t, b1 + l*3072, hbuf, nullptr, 3072, 768, 24);
        gemm_res_kernel<<<768, 256, 0, stream>>>(hbuf, w2_t, b2 + l*768, x, 768, 3072, 6);
    }
    cls_kernel<<<8, 256, 0, stream>>>(x, Wc, bc, (float*)d_out);
}

// Round 16
// 3203.052 us; speedup vs baseline: 1.0005x; 1.0005x over previous
//
#include <hip/hip_runtime.h>
#include <hip/hip_bf16.h>
#include <math.h>

// ---------------- constants ----------------
#define B_   8
#define S_   1024
#define D_   768
#define H_   12
#define HD_  64
#define L_   12
#define F_   3072
#define NTOK 8192   // B_*S_

typedef __bf16 bf16x8 __attribute__((ext_vector_type(8)));
typedef float  f32x4  __attribute__((ext_vector_type(4)));
typedef unsigned short u16;

static __device__ __forceinline__ unsigned short f2bf_bits(float f) {
    __hip_bfloat16 h = __float2bfloat16(f);
    return __builtin_bit_cast(unsigned short, h);
}
static __device__ __forceinline__ float bf2f(unsigned short u) {
    unsigned int t = ((unsigned int)u) << 16;
    return __builtin_bit_cast(float, t);
}
static __device__ __forceinline__ void gload16(const void* g, void* l) {
    __builtin_amdgcn_global_load_lds(
        (__attribute__((address_space(1))) void*)g,
        (__attribute__((address_space(3))) void*)l, 16, 0, 0);
}

// ---------------- fused: weight prep (blocks 0..1727) + LN1 (blocks 1728..3775) --------
__global__ __launch_bounds__(256)
void prep_ln_kernel(const float* __restrict__ Wq, const float* __restrict__ Wk,
                    const float* __restrict__ Wv, const float* __restrict__ Wo,
                    const float* __restrict__ W1, const float* __restrict__ W2,
                    int l, __hip_bfloat16* __restrict__ wbuf,
                    const float* __restrict__ xin, const float* __restrict__ gam,
                    const float* __restrict__ bet, __hip_bfloat16* __restrict__ xnout)
{
    __shared__ u16 T[64][68];
    if (blockIdx.x >= 1728) {
        // ---------------- LN path ----------------
        const int row  = (blockIdx.x - 1728)*4 + (threadIdx.x >> 6);
        const int lane = threadIdx.x & 63;
        const float* xr = xin + (size_t)row * D_;
        float v[12]; float s1 = 0.f, s2 = 0.f;
#pragma unroll
        for (int c = 0; c < 3; ++c) {
            float4 t = *(const float4*)(xr + c*256 + lane*4);
            v[c*4+0]=t.x; v[c*4+1]=t.y; v[c*4+2]=t.z; v[c*4+3]=t.w;
            s1 += t.x+t.y+t.z+t.w;
            s2 += t.x*t.x + t.y*t.y + t.z*t.z + t.w*t.w;
        }
#pragma unroll
        for (int off = 32; off > 0; off >>= 1) { s1 += __shfl_xor(s1, off); s2 += __shfl_xor(s2, off); }
        const float mean = s1 * (1.f/768.f);
        const float rstd = rsqrtf(s2*(1.f/768.f) - mean*mean + 1e-5f);
        unsigned short* op = (unsigned short*)xnout + (size_t)row * D_;
#pragma unroll
        for (int c = 0; c < 3; ++c) {
            const int base = c*256 + lane*4;
            float4 g = *(const float4*)(gam + base);
            float4 bb = *(const float4*)(bet + base);
            ushort4 pk;
            pk.x = f2bf_bits((v[c*4+0]-mean)*rstd*g.x + bb.x);
            pk.y = f2bf_bits((v[c*4+1]-mean)*rstd*g.y + bb.y);
            pk.z = f2bf_bits((v[c*4+2]-mean)*rstd*g.z + bb.z);
            pk.w = f2bf_bits((v[c*4+3]-mean)*rstd*g.w + bb.w);
            *(ushort4*)(op + base) = pk;
        }
        return;
    }
    // ---------------- prep path ----------------
    const int id = blockIdx.x;   // 0..1727
    const float* src; __hip_bfloat16* dst;
    int R, C, r0, c0;
    if (id < 432) {
        int dtile = id % 12, t = id / 12;
        int which = t / 12, h = t % 12;
        src = (which == 0 ? Wq : which == 1 ? Wk : Wv) + (size_t)(l*12 + h) * 768 * 64;
        dst = wbuf + (size_t)(which*768 + h*64) * 768;
        R = 768; C = 64; r0 = dtile * 64; c0 = 0;
    } else if (id < 576) {
        int t = id - 432;
        src = Wo + (size_t)l * 768 * 768;
        dst = wbuf + 1769472;
        R = 768; C = 768; r0 = (t / 12) * 64; c0 = (t % 12) * 64;
    } else if (id < 1152) {
        int t = id - 576;
        src = W1 + (size_t)l * 768 * 3072;
        dst = wbuf + 2359296;
        R = 768; C = 3072; r0 = (t % 12) * 64; c0 = (t / 12) * 64;
    } else {
        int t = id - 1152;
        src = W2 + (size_t)l * 3072 * 768;
        dst = wbuf + 4718592;
        R = 3072; C = 768; r0 = (t / 12) * 64; c0 = (t % 12) * 64;
    }
    const int t = threadIdx.x;
    const int row = t >> 2, part = t & 3;
#pragma unroll
    for (int j = 0; j < 4; ++j) {
        const int c4 = (part + j*4) * 4;
        float4 v = *(const float4*)(src + (size_t)(r0 + row) * C + c0 + c4);
        T[c4+0][row] = f2bf_bits(v.x);
        T[c4+1][row] = f2bf_bits(v.y);
        T[c4+2][row] = f2bf_bits(v.z);
        T[c4+3][row] = f2bf_bits(v.w);
    }
    __syncthreads();
    const int c = t >> 2;
    u16* drow = (u16*)dst + (size_t)(c0 + c) * R + r0;
#pragma unroll
    for (int j = 0; j < 4; ++j) {
        const int r4 = (part + j*4) * 4;
        ushort4 pk = *(const ushort4*)&T[c][r4];
        *(ushort4*)(drow + r4) = pk;
    }
}

__global__ __launch_bounds__(256)
void prep_bqkv_kernel(const float* __restrict__ bq, const float* __restrict__ bk,
                      const float* __restrict__ bv, float* __restrict__ bqkv)
{
    int i = blockIdx.x * 256 + threadIdx.x;   // < 12*2304
    int l = i / 2304, c = i % 2304;
    int which = c / 768, hk = c % 768;
    const float* src = which == 0 ? bq : which == 1 ? bk : bv;
    bqkv[i] = src[l*768 + hk];
}

// ---------------- embedding + LN -> x (fp32) ----------------
__global__ __launch_bounds__(256)
void embed_ln_kernel(const int* __restrict__ tokens, const float* __restrict__ tok_emb,
                     const float* __restrict__ pos_emb, const float* __restrict__ gam,
                     const float* __restrict__ bet, float* __restrict__ x)
{
    const int row  = blockIdx.x*4 + (threadIdx.x >> 6);
    const int lane = threadIdx.x & 63;
    const int s    = row & (S_-1);
    const int tok  = tokens[row];
    const float* te = tok_emb + (size_t)tok * D_;
    const float* pe = pos_emb + (size_t)s   * D_;
    float v[12]; float s1 = 0.f, s2 = 0.f;
#pragma unroll
    for (int c = 0; c < 3; ++c) {
        const int base = c*256 + lane*4;
        float4 a = *(const float4*)(te + base);
        float4 p = *(const float4*)(pe + base);
        float t0 = a.x+p.x, t1 = a.y+p.y, t2 = a.z+p.z, t3 = a.w+p.w;
        v[c*4+0]=t0; v[c*4+1]=t1; v[c*4+2]=t2; v[c*4+3]=t3;
        s1 += t0+t1+t2+t3;
        s2 += t0*t0 + t1*t1 + t2*t2 + t3*t3;
    }
#pragma unroll
    for (int off = 32; off > 0; off >>= 1) { s1 += __shfl_xor(s1, off); s2 += __shfl_xor(s2, off); }
    const float mean = s1 * (1.f/768.f);
    const float rstd = rsqrtf(s2*(1.f/768.f) - mean*mean + 1e-5f);
    float* xr = x + (size_t)row * D_;
#pragma unroll
    for (int c = 0; c < 3; ++c) {
        const int base = c*256 + lane*4;
        float4 g = *(const float4*)(gam + base);
        float4 bb = *(const float4*)(bet + base);
        float4 o;
        o.x = (v[c*4+0]-mean)*rstd*g.x + bb.x;
        o.y = (v[c*4+1]-mean)*rstd*g.y + bb.y;
        o.z = (v[c*4+2]-mean)*rstd*g.z + bb.z;
        o.w = (v[c*4+3]-mean)*rstd*g.w + bb.w;
        *(float4*)(xr + base) = o;
    }
}

// ---------------- LN: x (fp32) -> xn (bf16) ----------------
__global__ __launch_bounds__(256)
void ln_kernel(const float* __restrict__ xin, const float* __restrict__ gam,
               const float* __restrict__ bet, __hip_bfloat16* __restrict__ out)
{
    const int row  = blockIdx.x*4 + (threadIdx.x >> 6);
    const int lane = threadIdx.x & 63;
    const float* xr = xin + (size_t)row * D_;
    float v[12]; float s1 = 0.f, s2 = 0.f;
#pragma unroll
    for (int c = 0; c < 3; ++c) {
        float4 t = *(const float4*)(xr + c*256 + lane*4);
        v[c*4+0]=t.x; v[c*4+1]=t.y; v[c*4+2]=t.z; v[c*4+3]=t.w;
        s1 += t.x+t.y+t.z+t.w;
        s2 += t.x*t.x + t.y*t.y + t.z*t.z + t.w*t.w;
    }
#pragma unroll
    for (int off = 32; off > 0; off >>= 1) { s1 += __shfl_xor(s1, off); s2 += __shfl_xor(s2, off); }
    const float mean = s1 * (1.f/768.f);
    const float rstd = rsqrtf(s2*(1.f/768.f) - mean*mean + 1e-5f);
    unsigned short* op = (unsigned short*)out + (size_t)row * D_;
#pragma unroll
    for (int c = 0; c < 3; ++c) {
        const int base = c*256 + lane*4;
        float4 g = *(const float4*)(gam + base);
        float4 bb = *(const float4*)(bet + base);
        ushort4 pk;
        pk.x = f2bf_bits((v[c*4+0]-mean)*rstd*g.x + bb.x);
        pk.y = f2bf_bits((v[c*4+1]-mean)*rstd*g.y + bb.y);
        pk.z = f2bf_bits((v[c*4+2]-mean)*rstd*g.z + bb.z);
        pk.w = f2bf_bits((v[c*4+3]-mean)*rstd*g.w + bb.w);
        *(ushort4*)(op + base) = pk;
    }
}

// ---------------- GEMM 256x128, 8 waves (64x64 each), BK=32, counted-vmcnt pipeline ----
template<int EPI>
__global__ __launch_bounds__(512, 2)
void gemm256_kernel(const __hip_bfloat16* __restrict__ A,
                    const __hip_bfloat16* __restrict__ Bt,
                    const float* __restrict__ bias,
                    __hip_bfloat16* __restrict__ outb,
                    __hip_bfloat16* __restrict__ outv,
                    int N, int K, int nTiles)
{
    __shared__ __align__(16) char smem[49152];
    char* const As0 = smem;            // 16 KB: A [256][32] bf16, swizzled
    char* const As1 = smem + 16384;
    char* const Bs0 = smem + 32768;    // 8 KB: B [128][32]
    char* const Bs1 = smem + 40960;

    const int tid  = threadIdx.x;
    const int lane = tid & 63;
    const int wid  = tid >> 6;          // 0..7

    const int nwg   = gridDim.x;
    const int chunk = nwg >> 3;
    const int bid   = blockIdx.x;
    const int swz   = (bid & 7) * chunk + (bid >> 3);
    const int m0 = (swz / nTiles) * 256;
    const int n0 = (swz % nTiles) * 128;

    const int l4 = lane >> 2;                              // 0..15
    const int sswz = ((lane & 3) ^ ((l4 >> 1) & 3)) * 8;   // source col (elements)
    const __hip_bfloat16* aSrc = A  + (size_t)(m0 + wid*16 + l4) * K + sswz;
    const __hip_bfloat16* bSrc = Bt + (size_t)(n0 + wid*16 + l4) * K + sswz;
    const int sOff = wid*1024 + lane*16;

    f32x4 acc[4][4] = {};
    const int wm = wid >> 1, wn = wid & 1;   // 4 m-waves x 2 n-waves
    const int cl = lane & 15, hi = lane >> 4;

    int aoff[4], boff[4];
#pragma unroll
    for (int m = 0; m < 4; ++m) {
        const int row = wm*64 + m*16 + cl;                 // 0..255
        aoff[m] = row*64 + ((hi ^ ((row >> 1) & 3)) << 4);
    }
#pragma unroll
    for (int n = 0; n < 4; ++n) {
        const int row = wn*64 + n*16 + cl;                 // 0..127
        boff[n] = row*64 + ((hi ^ ((row >> 1) & 3)) << 4);
    }

    auto STAGE = [&](char* aBuf, char* bBuf, int kt) {
        gload16(aSrc + kt,                  aBuf + sOff);
        gload16(aSrc + kt + (size_t)128*K,  aBuf + 8192 + sOff);
        gload16(bSrc + kt,                  bBuf + sOff);
    };

    const int NT = K >> 5;   // K/32
    STAGE(As0, Bs0, 0);
    STAGE(As1, Bs1, 32);

    for (int t = 0; t < NT; ++t) {
        if (t < NT - 1) asm volatile("s_waitcnt vmcnt(3)" ::: "memory");
        else            asm volatile("s_waitcnt vmcnt(0)" ::: "memory");
        __builtin_amdgcn_s_barrier();

        char* const ac = (t & 1) ? As1 : As0;
        char* const bc = (t & 1) ? Bs1 : Bs0;
        bf16x8 af[4], bfr[4];
#pragma unroll
        for (int m = 0; m < 4; ++m) af[m]  = *(const bf16x8*)(ac + aoff[m]);
#pragma unroll
        for (int n = 0; n < 4; ++n) bfr[n] = *(const bf16x8*)(bc + boff[n]);
        asm volatile("s_waitcnt lgkmcnt(0)" ::: "memory");
        __builtin_amdgcn_sched_barrier(0);
        __builtin_amdgcn_s_barrier();

        if (t + 2 < NT) STAGE(ac, bc, (t + 2) << 5);   // overwrite just-consumed buffer

        __builtin_amdgcn_s_setprio(1);
#pragma unroll
        for (int m = 0; m < 4; ++m)
#pragma unroll
            for (int n = 0; n < 4; ++n)
                acc[m][n] = __builtin_amdgcn_mfma_f32_16x16x32_bf16(af[m], bfr[n], acc[m][n], 0, 0, 0);
        __builtin_amdgcn_s_setprio(0);
    }

    const bool vpath = (EPI == 0) && (n0 >= 1536);

    if (!vpath) {
        // bf16 repack through LDS in two 128-row halves -> coalesced float4 stores
        const int strideN = (EPI == 0) ? 1536 : N;
#pragma unroll
        for (int half = 0; half < 2; ++half) {
            __syncthreads();
            if ((wm >> 1) == half) {
#pragma unroll
                for (int n = 0; n < 4; ++n) {
                    const int col2 = wn*64 + n*16 + cl;
                    const float bv = bias[n0 + col2];
#pragma unroll
                    for (int m = 0; m < 4; ++m) {
#pragma unroll
                        for (int i = 0; i < 4; ++i) {
                            const int row = (wm & 1)*64 + m*16 + hi*4 + i;  // 0..127
                            float v = acc[m][n][i] + bv;
                            if constexpr (EPI == 1) {
                                const float y = 0.7978845608f * (v + 0.044715f*v*v*v);
                                const float e = __expf(-2.0f * fabsf(y));
                                const float th = (1.0f - e) / (1.0f + e);
                                v = 0.5f * v * (1.0f + copysignf(th, y));
                            }
                            *(u16*)(smem + row*256 + ((((col2 >> 3) ^ (row & 15))) << 4)
                                         + ((col2 & 7) << 1)) = f2bf_bits(v);
                        }
                    }
                }
            }
            __syncthreads();
            const int r = tid >> 2;        // 0..127
            const int part = tid & 3;
            char* dst = (char*)outb + ((size_t)(m0 + half*128 + r) * strideN + n0) * 2;
#pragma unroll
            for (int j = 0; j < 4; ++j) {
                const int ch = part + j*4;               // 0..15
                float4 vv = *(const float4*)(smem + r*256 + ((ch ^ (r & 15)) << 4));
                *(float4*)(dst + ch*16) = vv;
            }
        }
    } else {
        // V -> V^T via LDS transpose, two 128-row halves
        const int hdbase = n0 - 1536;
        const int bb = m0 >> 10;
#pragma unroll
        for (int half = 0; half < 2; ++half) {
            __syncthreads();
            if ((wm >> 1) == half) {
#pragma unroll
                for (int n = 0; n < 4; ++n) {
                    const int hdl = wn*64 + n*16 + cl;     // 0..127
                    const float bv = bias[n0 + hdl];
#pragma unroll
                    for (int m = 0; m < 4; ++m) {
                        const int sl = (wm & 1)*64 + m*16 + hi*4;   // s-local 0..127
                        ushort4 pk;
                        pk.x = f2bf_bits(acc[m][n][0] + bv);
                        pk.y = f2bf_bits(acc[m][n][1] + bv);
                        pk.z = f2bf_bits(acc[m][n][2] + bv);
                        pk.w = f2bf_bits(acc[m][n][3] + bv);
                        *(ushort4*)(smem + hdl*256 + ((((sl >> 3) ^ (hdl & 15))) << 4)
                                         + (sl & 7)*2) = pk;
                    }
                }
            }
            __syncthreads();
            const int hdl2 = tid >> 2;        // 0..127
            const int q4   = tid & 3;
            u16* dst = (u16*)outv + ((size_t)(bb*768) + hdbase + hdl2)*1024
                                  + (m0 & 1023) + half*128;
#pragma unroll
            for (int j = 0; j < 4; ++j) {
                const int ch = q4*4 + j;                  // 0..15
                const int slot = ch ^ (hdl2 & 15);
                *(float4*)((char*)dst + ch*16) = *(const float4*)(smem + hdl2*256 + (slot << 4));
            }
        }
    }
}

// ---------------- GEMM 64x128, 4 waves, counted-vmcnt dbuf: outf += A*Bt^T + bias ----
__global__ __launch_bounds__(256)
void gemm_res_kernel(const __hip_bfloat16* __restrict__ A,
                     const __hip_bfloat16* __restrict__ Bt,
                     const float* __restrict__ bias,
                     float* __restrict__ outf,
                     int N, int K, int nTiles)
{
    __shared__ __align__(16) char smem[49152];
    char* const As0 = smem;            // 8 KB [64][64]
    char* const As1 = smem + 8192;
    char* const Bs0 = smem + 16384;    // 16 KB [128][64]
    char* const Bs1 = smem + 32768;

    const int tid  = threadIdx.x;
    const int lane = tid & 63;
    const int wid  = tid >> 6;

    const int nwg   = gridDim.x;
    const int chunk = nwg >> 3;
    const int bid   = blockIdx.x;
    const int swz   = (bid & 7) * chunk + (bid >> 3);
    const int m0 = (swz / nTiles) * 64;
    const int n0 = (swz % nTiles) * 128;

    const int lrow = lane >> 3;                 // 0..7
    const int scol = ((lane & 7) ^ lrow) * 8;   // swizzled source col
    const __hip_bfloat16* aSrc = A  + (size_t)(m0 + wid*16 + lrow) * K + scol;
    const __hip_bfloat16* bSrc = Bt + (size_t)(n0 + wid*32 + lrow) * K + scol;
    const int aOff = wid*2048 + lane*16;
    const int bOff = wid*4096 + lane*16;

    f32x4 acc[2][4] = {};
    const int wm = wid >> 1, wn = wid & 1;
    const int cl = lane & 15, hi = lane >> 4;

    auto STAGE = [&](char* aBuf, char* bBuf, int kt) {
#pragma unroll
        for (int i = 0; i < 2; ++i)
            gload16(aSrc + kt + (size_t)i*8*K, aBuf + aOff + i*1024);
#pragma unroll
        for (int i = 0; i < 4; ++i)
            gload16(bSrc + kt + (size_t)i*8*K, bBuf + bOff + i*1024);
    };

    const int NT = K >> 6;   // K/64
    STAGE(As0, Bs0, 0);
    STAGE(As1, Bs1, 64);

    for (int t = 0; t < NT; ++t) {
        if (t < NT - 1) asm volatile("s_waitcnt vmcnt(6)" ::: "memory");
        else            asm volatile("s_waitcnt vmcnt(0)" ::: "memory");
        __builtin_amdgcn_s_barrier();

        char* const ac = (t & 1) ? As1 : As0;
        char* const bc = (t & 1) ? Bs1 : Bs0;
        bf16x8 af[2][2], bfr[2][4];
#pragma unroll
        for (int kk = 0; kk < 2; ++kk) {
#pragma unroll
            for (int m = 0; m < 2; ++m) {
                const int row  = wm*32 + m*16 + cl;
                const int slot = ((kk<<2) + hi) ^ (row & 7);
                af[kk][m] = *(const bf16x8*)(ac + row*128 + slot*16);
            }
#pragma unroll
            for (int n = 0; n < 4; ++n) {
                const int row  = wn*64 + n*16 + cl;
                const int slot = ((kk<<2) + hi) ^ (row & 7);
                bfr[kk][n] = *(const bf16x8*)(bc + row*128 + slot*16);
            }
        }
        asm volatile("s_waitcnt lgkmcnt(0)" ::: "memory");
        __builtin_amdgcn_sched_barrier(0);
        __builtin_amdgcn_s_barrier();

        if (t + 2 < NT) STAGE(ac, bc, (t + 2) << 6);

        __builtin_amdgcn_s_setprio(1);
#pragma unroll
        for (int kk = 0; kk < 2; ++kk)
#pragma unroll
            for (int m = 0; m < 2; ++m)
#pragma unroll
                for (int n = 0; n < 4; ++n)
                    acc[m][n] = __builtin_amdgcn_mfma_f32_16x16x32_bf16(af[kk][m], bfr[kk][n], acc[m][n], 0, 0, 0);
        __builtin_amdgcn_s_setprio(0);
    }

    __syncthreads();   // staging LDS dead; reuse for fp32 repack

#pragma unroll
    for (int n = 0; n < 4; ++n) {
        const int col = wn*64 + n*16 + cl;
        const float bv = bias[n0 + col];
#pragma unroll
        for (int m = 0; m < 2; ++m) {
#pragma unroll
            for (int i = 0; i < 4; ++i) {
                const int row = wm*32 + m*16 + hi*4 + i;
                *(float*)(smem + row*512 + ((((col >> 2) ^ (row & 31))) << 4)
                               + ((col & 3) << 2)) = acc[m][n][i] + bv;
            }
        }
    }
    __syncthreads();
    const int r = tid >> 2;
    const int part = tid & 3;
    float* drow = outf + (size_t)(m0 + r) * N + n0;
#pragma unroll
    for (int j = 0; j < 8; ++j) {
        const int ch = part + j*4;
        f32x4 vv = *(const f32x4*)(smem + r*512 + ((ch ^ (r & 31)) << 4));
        float* dp = drow + ch*4;
        f32x4 g = *(const f32x4*)dp;
        g += vv;
        *(f32x4*)dp = g;
    }
}

// ---------------- flash attention, MFMA bf16 ----------------
// 4 waves x 32 q-rows (2 q-groups of 16) = 128 q-rows/block; halves per-q-row
// LDS K/V read duplication vs the 8-wave/16-row layout. Inline PV (R13 structure).
__global__ __launch_bounds__(256)
void attn_kernel(const __hip_bfloat16* __restrict__ qkb, const __hip_bfloat16* __restrict__ vtb,
                 __hip_bfloat16* __restrict__ attno)
{
    __shared__ __align__(16) char Ks[2][8192];  // [t 64][d 64] bf16, slot^=(t&7)
    __shared__ __align__(16) char Vs[2][8192];  // [d 64][t 64] bf16, slot^=(d&7)
    __shared__ __align__(16) char Ps[16384];    // per-wave P: [q 32][t 64], slot^=(q&7)

    const u16* qk = (const u16*)qkb;
    const u16* vt = (const u16*)vtb;
    const int nwg = gridDim.x, bid = blockIdx.x, chunk = nwg >> 3;
    const int swz = (bid & 7) * chunk + (bid >> 3);
    const int bh = swz >> 3, qb = swz & 7;
    const int b = bh / H_, h = bh % H_;
    const int tid = threadIdx.x;
    const int lane = tid & 63, wid = tid >> 6;   // wid 0..3
    const int cl = lane & 15, hi = lane >> 4;
    const size_t browq = (size_t)(b*S_ + qb*128);

    // Q fragments for 2 q-groups (rows wid*32 + g*16 + cl), pre-scaled by log2(e)/8
    bf16x8 qf[2][2];
#pragma unroll
    for (int g = 0; g < 2; ++g) {
        const float qs = 0.1803368801f;
        const u16* qp = qk + (browq + wid*32 + g*16 + cl)*1536 + h*64;
        u16 qt[16];
#pragma unroll
        for (int j = 0; j < 8; ++j) {
            qt[j]     = f2bf_bits(bf2f(qp[hi*8 + j]) * qs);
            qt[8 + j] = f2bf_bits(bf2f(qp[32 + hi*8 + j]) * qs);
        }
        qf[g][0] = *(const bf16x8*)&qt[0];
        qf[g][1] = *(const bf16x8*)&qt[8];
    }

    // staging: wave covers 16 rows (2 gload rounds of 8)
    const int lrow = lane >> 3;                  // 0..7
    const int scol = ((lane & 7) ^ lrow) * 8;    // swizzled source col
    const u16* kbase = qk + ((size_t)b*S_ + wid*16 + lrow)*1536 + 768 + h*64 + scol;
    const u16* vbase = vt + (((size_t)(b*H_ + h))*64 + wid*16 + lrow)*1024 + scol;
    const int ldst = wid*2048 + lane*16;

    char* pbase = Ps + wid*4096;

    f32x4 acc_o[2][4] = {};
    float m_run = -1e30f;                        // log2 domain
    float l_part[2][4] = {};

    {
        gload16(kbase,                  Ks[0] + ldst);
        gload16(kbase + (size_t)8*1536, Ks[0] + ldst + 1024);
        gload16(vbase,                  Vs[0] + ldst);
        gload16(vbase + 8*1024,         Vs[0] + ldst + 1024);
    }

    for (int t = 0; t < 16; ++t) {
        __syncthreads();
        if (t < 15) {
            const int nb = (t+1) & 1;
            const u16* kn = kbase + (size_t)(t+1)*64*1536;
            const u16* vn = vbase + (t+1)*64;
            gload16(kn,                  Ks[nb] + ldst);
            gload16(kn + (size_t)8*1536, Ks[nb] + ldst + 1024);
            gload16(vn,                  Vs[nb] + ldst);
            gload16(vn + 8*1024,         Vs[nb] + ldst + 1024);
        }
        const char* ks = Ks[t & 1];
        const char* vs = Vs[t & 1];

        // QK(t): kf read once, used by both q-groups
        f32x4 sc[2][4] = {};
#pragma unroll
        for (int kk = 0; kk < 2; ++kk) {
            bf16x8 kf[4];
#pragma unroll
            for (int n = 0; n < 4; ++n) {
                const int row = n*16 + cl;
                kf[n] = *(const bf16x8*)(ks + row*128 + (((kk*4 + hi) ^ (cl & 7)) << 4));
            }
#pragma unroll
            for (int g = 0; g < 2; ++g)
#pragma unroll
                for (int n = 0; n < 4; ++n)
                    sc[g][n] = __builtin_amdgcn_mfma_f32_16x16x32_bf16(qf[g][kk], kf[n], sc[g][n], 0, 0, 0);
        }

        // softmax (log2 domain, scale folded into Q); shared running max
        float gmax;
        {
            float a0 = fmaxf(fmaxf(sc[0][0][0], sc[0][0][1]), fmaxf(sc[0][0][2], sc[0][0][3]));
#pragma unroll
            for (int g = 0; g < 2; ++g)
#pragma unroll
                for (int n = 0; n < 4; ++n) {
                    if (g == 0 && n == 0) continue;
                    a0 = fmaxf(a0, fmaxf(fmaxf(sc[g][n][0], sc[g][n][1]), fmaxf(sc[g][n][2], sc[g][n][3])));
                }
            gmax = a0;
        }
        gmax = fmaxf(gmax, __shfl_xor(gmax, 1));
        gmax = fmaxf(gmax, __shfl_xor(gmax, 2));
        gmax = fmaxf(gmax, __shfl_xor(gmax, 4));
        gmax = fmaxf(gmax, __shfl_xor(gmax, 8));
        if (gmax > m_run + 5.7707801636f) {      // 4*log2(e): P bounded by e^4
            const float corr = exp2f(m_run - gmax);
            m_run = gmax;
#pragma unroll
            for (int g = 0; g < 2; ++g)
#pragma unroll
                for (int i = 0; i < 4; ++i) l_part[g][i] *= corr;
#pragma unroll
            for (int g = 0; g < 2; ++g)
#pragma unroll
                for (int nd = 0; nd < 4; ++nd)
#pragma unroll
                    for (int i = 0; i < 4; ++i)
                        acc_o[g][nd][i] *= corr;
        }

        // P -> LDS (per-wave region, [q 32][t 64])
#pragma unroll
        for (int g = 0; g < 2; ++g) {
#pragma unroll
            for (int n = 0; n < 4; ++n) {
#pragma unroll
                for (int i = 0; i < 4; ++i) {
                    const float e = exp2f(sc[g][n][i] - m_run);
                    l_part[g][i] += e;
                    const int q = g*16 + hi*4 + i;
                    const int slot = (n*2 + (cl >> 3)) ^ (q & 7);
                    *(u16*)(pbase + q*128 + slot*16 + (cl & 7)*2) = f2bf_bits(e);
                }
            }
        }

        asm volatile("s_waitcnt lgkmcnt(0)" ::: "memory");
        __builtin_amdgcn_sched_barrier(0);

        // PV: vf read once per kk, used by both q-groups
#pragma unroll
        for (int kk = 0; kk < 2; ++kk) {
            bf16x8 pf[2];
#pragma unroll
            for (int g = 0; g < 2; ++g) {
                const int qrow = g*16 + cl;
                pf[g] = *(const bf16x8*)(pbase + qrow*128 + (((kk*4 + hi) ^ (cl & 7)) << 4));
            }
            bf16x8 vf[4];
#pragma unroll
            for (int nd = 0; nd < 4; ++nd) {
                const int d = nd*16 + cl;
                vf[nd] = *(const bf16x8*)(vs + d*128 + (((kk*4 + hi) ^ (d & 7)) << 4));
            }
#pragma unroll
            for (int g = 0; g < 2; ++g)
#pragma unroll
                for (int nd = 0; nd < 4; ++nd)
                    acc_o[g][nd] = __builtin_amdgcn_mfma_f32_16x16x32_bf16(pf[g], vf[nd], acc_o[g][nd], 0, 0, 0);
        }
    }

    u16* op = (u16*)attno;
#pragma unroll
    for (int g = 0; g < 2; ++g) {
#pragma unroll
        for (int i = 0; i < 4; ++i) {
            float l = l_part[g][i];
            l += __shfl_xor(l, 1);
            l += __shfl_xor(l, 2);
            l += __shfl_xor(l, 4);
            l += __shfl_xor(l, 8);
            const float inv = 1.f / l;
            const size_t row = browq + wid*32 + g*16 + hi*4 + i;
#pragma unroll
            for (int nd = 0; nd < 4; ++nd)
                op[row*768 + h*64 + nd*16 + cl] = f2bf_bits(acc_o[g][nd][i] * inv);
        }
    }
}

// ---------------- classifier ----------------
__global__ __launch_bounds__(256)
void cls_kernel(const float* __restrict__ x, const float* __restrict__ Wc,
                const float* __restrict__ bc, float* __restrict__ out)
{
    const int b = blockIdx.x;
    const float* xr = x + (size_t)b * S_ * D_;
    float a0 = 0.f, a1 = 0.f;
    for (int d = threadIdx.x; d < 768; d += 256) {
        float xv = xr[d];
        a0 += xv * Wc[d*2+0];
        a1 += xv * Wc[d*2+1];
    }
#pragma unroll
    for (int off = 32; off > 0; off >>= 1) { a0 += __shfl_xor(a0, off); a1 += __shfl_xor(a1, off); }
    __shared__ float r0[4], r1[4];
    const int w = threadIdx.x >> 6;
    if ((threadIdx.x & 63) == 0) { r0[w] = a0; r1[w] = a1; }
    __syncthreads();
    if (threadIdx.x == 0) {
        out[b*2+0] = r0[0]+r0[1]+r0[2]+r0[3] + bc[0];
        out[b*2+1] = r1[0]+r1[1]+r1[2]+r1[3] + bc[1];
    }
}

// ---------------- launch ----------------
extern "C" void kernel_launch(void* const* d_in, const int* in_sizes, int n_in,
                              void* d_out, int out_size, void* d_ws, size_t ws_size,
                              hipStream_t stream)
{
    const int*   tokens  = (const int*)  d_in[0];
    const float* tok_emb = (const float*)d_in[1];
    const float* pos_emb = (const float*)d_in[2];
    const float* e_s     = (const float*)d_in[3];
    const float* e_b     = (const float*)d_in[4];
    const float* Wq      = (const float*)d_in[5];
    const float* bq      = (const float*)d_in[6];
    const float* Wk      = (const float*)d_in[7];
    const float* bk      = (const float*)d_in[8];
    const float* Wv      = (const float*)d_in[9];
    const float* bv      = (const float*)d_in[10];
    const float* Wo      = (const float*)d_in[11];
    const float* bo      = (const float*)d_in[12];
    const float* l1s     = (const float*)d_in[13];
    const float* l1b     = (const float*)d_in[14];
    const float* l2s     = (const float*)d_in[15];
    const float* l2b     = (const float*)d_in[16];
    const float* W1      = (const float*)d_in[17];
    const float* b1      = (const float*)d_in[18];
    const float* W2      = (const float*)d_in[19];
    const float* b2      = (const float*)d_in[20];
    const float* Wc      = (const float*)d_in[21];
    const float* bc      = (const float*)d_in[22];
    (void)in_sizes; (void)n_in; (void)out_size;

    if (ws_size < 102346752) return;   // need ~102.4 MB

    char* ws = (char*)d_ws;
    __hip_bfloat16* wbuf = (__hip_bfloat16*)(ws + 0);          // 14,155,776 B
    float*          bqkv = (float*)(ws + 14155776);            //    110,592 B
    float*          x    = (float*)(ws + 14266368);            // 25,165,824 B
    __hip_bfloat16* xn   = (__hip_bfloat16*)(ws + 39432192);   // 12,582,912 B
    __hip_bfloat16* qk   = (__hip_bfloat16*)(ws + 52015104);   // 25,165,824 B [8192][1536]
    __hip_bfloat16* vT   = (__hip_bfloat16*)(ws + 77180928);   // 12,582,912 B [b*768+hd][1024]
    __hip_bfloat16* att  = (__hip_bfloat16*)(ws + 89763840);   // 12,582,912 B (end 102,346,752)
    __hip_bfloat16* hbuf = qk;                                 // aliases qk+vT+att (50,331,648 B)

    __hip_bfloat16* wqkv_t = wbuf;
    __hip_bfloat16* wo_t   = wbuf + 1769472;
    __hip_bfloat16* w1_t   = wbuf + 2359296;
    __hip_bfloat16* w2_t   = wbuf + 4718592;

    prep_bqkv_kernel<<<108, 256, 0, stream>>>(bq, bk, bv, bqkv);
    embed_ln_kernel<<<2048, 256, 0, stream>>>(tokens, tok_emb, pos_emb, e_s, e_b, x);

    for (int l = 0; l < L_; ++l) {
        prep_ln_kernel<<<3776, 256, 0, stream>>>(Wq, Wk, Wv, Wo, W1, W2, l, wbuf,
                                                 x, l1s + l*768, l1b + l*768, xn);
        gemm256_kernel<0><<<576, 512, 0, stream>>>(xn, wqkv_t, bqkv + l*2304, qk, vT, 2304, 768, 18);
        attn_kernel<<<768, 256, 0, stream>>>(qk, vT, att);
        gemm_res_kernel<<<768, 256, 0, stream>>>(att, wo_t, bo + l*768, x, 768, 768, 6);
        ln_kernel<<<2048, 256, 0, stream>>>(x, l2s + l*768, l2b + l*768, xn);
        gemm256_kernel<1><<<768, 512, 0, stream>>>(xn, w1_t, b1 + l*3072, hbuf, nullptr, 3072, 768, 24);
        gemm_res_kernel<<<768, 256, 0, stream>>>(hbuf, w2_t, b2 + l*768, x, 768, 3072, 6);
    }
    cls_kernel<<<8, 256, 0, stream>>>(x, Wc, bc, (float*)d_out);
}

// Round 17
// 2947.254 us; speedup vs baseline: 1.0873x; 1.0868x over previous
//
#include <hip/hip_runtime.h>
#include <hip/hip_bf16.h>
#include <math.h>

// ---------------- constants ----------------
#define B_   8
#define S_   1024
#define D_   768
#define H_   12
#define HD_  64
#define L_   12
#define F_   3072
#define NTOK 8192   // B_*S_

typedef __bf16 bf16x8 __attribute__((ext_vector_type(8)));
typedef float  f32x4  __attribute__((ext_vector_type(4)));
typedef unsigned short u16;

static __device__ __forceinline__ unsigned short f2bf_bits(float f) {
    __hip_bfloat16 h = __float2bfloat16(f);
    return __builtin_bit_cast(unsigned short, h);
}
static __device__ __forceinline__ float bf2f(unsigned short u) {
    unsigned int t = ((unsigned int)u) << 16;
    return __builtin_bit_cast(float, t);
}
static __device__ __forceinline__ void gload16(const void* g, void* l) {
    __builtin_amdgcn_global_load_lds(
        (__attribute__((address_space(1))) void*)g,
        (__attribute__((address_space(3))) void*)l, 16, 0, 0);
}

// ---------------- weight prep: fp32 [R][C] -> bf16 transposed [C][R] ----------------
__global__ __launch_bounds__(256)
void prep_layer_kernel(const float* __restrict__ Wq, const float* __restrict__ Wk,
                       const float* __restrict__ Wv, const float* __restrict__ Wo,
                       const float* __restrict__ W1, const float* __restrict__ W2,
                       int l, __hip_bfloat16* __restrict__ wbuf)
{
    const int id = blockIdx.x;   // 0..1727
    const float* src; __hip_bfloat16* dst;
    int R, C, r0, c0;
    if (id < 432) {                       // q/k/v heads: src [768][64] per (which,h)
        int dtile = id % 12, t = id / 12; // t = which*12 + h
        int which = t / 12, h = t % 12;
        src = (which == 0 ? Wq : which == 1 ? Wk : Wv) + (size_t)(l*12 + h) * 768 * 64;
        dst = wbuf + (size_t)(which*768 + h*64) * 768;
        R = 768; C = 64; r0 = dtile * 64; c0 = 0;
    } else if (id < 576) {                // Wo: [768][768]
        int t = id - 432;
        src = Wo + (size_t)l * 768 * 768;
        dst = wbuf + 1769472;
        R = 768; C = 768; r0 = (t / 12) * 64; c0 = (t % 12) * 64;
    } else if (id < 1152) {               // W1: [768][3072]
        int t = id - 576;
        src = W1 + (size_t)l * 768 * 3072;
        dst = wbuf + 2359296;
        R = 768; C = 3072; r0 = (t % 12) * 64; c0 = (t / 12) * 64;
    } else {                              // W2: [3072][768]
        int t = id - 1152;
        src = W2 + (size_t)l * 3072 * 768;
        dst = wbuf + 4718592;
        R = 3072; C = 768; r0 = (t / 12) * 64; c0 = (t % 12) * 64;
    }
    __shared__ u16 T[64][68];             // transposed bf16 tile, padded
    const int t = threadIdx.x;
    const int row = t >> 2, part = t & 3;
#pragma unroll
    for (int j = 0; j < 4; ++j) {
        const int c4 = (part + j*4) * 4;
        float4 v = *(const float4*)(src + (size_t)(r0 + row) * C + c0 + c4);
        T[c4+0][row] = f2bf_bits(v.x);
        T[c4+1][row] = f2bf_bits(v.y);
        T[c4+2][row] = f2bf_bits(v.z);
        T[c4+3][row] = f2bf_bits(v.w);
    }
    __syncthreads();
    const int c = t >> 2;
    u16* drow = (u16*)dst + (size_t)(c0 + c) * R + r0;
#pragma unroll
    for (int j = 0; j < 4; ++j) {
        const int r4 = (part + j*4) * 4;
        ushort4 pk = *(const ushort4*)&T[c][r4];
        *(ushort4*)(drow + r4) = pk;
    }
}

__global__ __launch_bounds__(256)
void prep_bqkv_kernel(const float* __restrict__ bq, const float* __restrict__ bk,
                      const float* __restrict__ bv, float* __restrict__ bqkv)
{
    int i = blockIdx.x * 256 + threadIdx.x;   // < 12*2304
    int l = i / 2304, c = i % 2304;
    int which = c / 768, hk = c % 768;
    const float* src = which == 0 ? bq : which == 1 ? bk : bv;
    bqkv[i] = src[l*768 + hk];
}

// ---------------- embedding + LN -> x (fp32) ----------------
__global__ __launch_bounds__(256)
void embed_ln_kernel(const int* __restrict__ tokens, const float* __restrict__ tok_emb,
                     const float* __restrict__ pos_emb, const float* __restrict__ gam,
                     const float* __restrict__ bet, float* __restrict__ x)
{
    const int row  = blockIdx.x*4 + (threadIdx.x >> 6);
    const int lane = threadIdx.x & 63;
    const int s    = row & (S_-1);
    const int tok  = tokens[row];
    const float* te = tok_emb + (size_t)tok * D_;
    const float* pe = pos_emb + (size_t)s   * D_;
    float v[12]; float s1 = 0.f, s2 = 0.f;
#pragma unroll
    for (int c = 0; c < 3; ++c) {
        const int base = c*256 + lane*4;
        float4 a = *(const float4*)(te + base);
        float4 p = *(const float4*)(pe + base);
        float t0 = a.x+p.x, t1 = a.y+p.y, t2 = a.z+p.z, t3 = a.w+p.w;
        v[c*4+0]=t0; v[c*4+1]=t1; v[c*4+2]=t2; v[c*4+3]=t3;
        s1 += t0+t1+t2+t3;
        s2 += t0*t0 + t1*t1 + t2*t2 + t3*t3;
    }
#pragma unroll
    for (int off = 32; off > 0; off >>= 1) { s1 += __shfl_xor(s1, off); s2 += __shfl_xor(s2, off); }
    const float mean = s1 * (1.f/768.f);
    const float rstd = rsqrtf(s2*(1.f/768.f) - mean*mean + 1e-5f);
    float* xr = x + (size_t)row * D_;
#pragma unroll
    for (int c = 0; c < 3; ++c) {
        const int base = c*256 + lane*4;
        float4 g = *(const float4*)(gam + base);
        float4 bb = *(const float4*)(bet + base);
        float4 o;
        o.x = (v[c*4+0]-mean)*rstd*g.x + bb.x;
        o.y = (v[c*4+1]-mean)*rstd*g.y + bb.y;
        o.z = (v[c*4+2]-mean)*rstd*g.z + bb.z;
        o.w = (v[c*4+3]-mean)*rstd*g.w + bb.w;
        *(float4*)(xr + base) = o;
    }
}

// ---------------- LN: x (fp32) -> xn (bf16) ----------------
__global__ __launch_bounds__(256)
void ln_kernel(const float* __restrict__ xin, const float* __restrict__ gam,
               const float* __restrict__ bet, __hip_bfloat16* __restrict__ out)
{
    const int row  = blockIdx.x*4 + (threadIdx.x >> 6);
    const int lane = threadIdx.x & 63;
    const float* xr = xin + (size_t)row * D_;
    float v[12]; float s1 = 0.f, s2 = 0.f;
#pragma unroll
    for (int c = 0; c < 3; ++c) {
        float4 t = *(const float4*)(xr + c*256 + lane*4);
        v[c*4+0]=t.x; v[c*4+1]=t.y; v[c*4+2]=t.z; v[c*4+3]=t.w;
        s1 += t.x+t.y+t.z+t.w;
        s2 += t.x*t.x + t.y*t.y + t.z*t.z + t.w*t.w;
    }
#pragma unroll
    for (int off = 32; off > 0; off >>= 1) { s1 += __shfl_xor(s1, off); s2 += __shfl_xor(s2, off); }
    const float mean = s1 * (1.f/768.f);
    const float rstd = rsqrtf(s2*(1.f/768.f) - mean*mean + 1e-5f);
    unsigned short* op = (unsigned short*)out + (size_t)row * D_;
#pragma unroll
    for (int c = 0; c < 3; ++c) {
        const int base = c*256 + lane*4;
        float4 g = *(const float4*)(gam + base);
        float4 bb = *(const float4*)(bet + base);
        ushort4 pk;
        pk.x = f2bf_bits((v[c*4+0]-mean)*rstd*g.x + bb.x);
        pk.y = f2bf_bits((v[c*4+1]-mean)*rstd*g.y + bb.y);
        pk.z = f2bf_bits((v[c*4+2]-mean)*rstd*g.z + bb.z);
        pk.w = f2bf_bits((v[c*4+3]-mean)*rstd*g.w + bb.w);
        *(ushort4*)(op + base) = pk;
    }
}

// ---------------- GEMM 256x128, 8 waves (64x64 each), BK=32, counted-vmcnt pipeline ----
// 2-deep prefetch; s_waitcnt vmcnt(3) (not 0) per step; raw s_barrier pair.
// EPI 0: QKV — n0<1536: Q/K -> outb stride 1536 (direct); else V -> outv = V^T (LDS transpose)
// EPI 1: gelu(tanh) -> outb stride N (direct)
template<int EPI>
__global__ __launch_bounds__(512, 2)
void gemm256_kernel(const __hip_bfloat16* __restrict__ A,
                    const __hip_bfloat16* __restrict__ Bt,
                    const float* __restrict__ bias,
                    __hip_bfloat16* __restrict__ outb,
                    __hip_bfloat16* __restrict__ outv,
                    int N, int K, int nTiles)
{
    __shared__ __align__(16) char smem[49152];
    char* const As0 = smem;            // 16 KB: A [256][32] bf16, swizzled
    char* const As1 = smem + 16384;
    char* const Bs0 = smem + 32768;    // 8 KB: B [128][32]
    char* const Bs1 = smem + 40960;

    const int tid  = threadIdx.x;
    const int lane = tid & 63;
    const int wid  = tid >> 6;          // 0..7

    const int nwg   = gridDim.x;
    const int chunk = nwg >> 3;
    const int bid   = blockIdx.x;
    const int swz   = (bid & 7) * chunk + (bid >> 3);
    const int m0 = (swz / nTiles) * 256;
    const int n0 = (swz % nTiles) * 128;

    const int l4 = lane >> 2;                              // 0..15
    const int sswz = ((lane & 3) ^ ((l4 >> 1) & 3)) * 8;   // source col (elements)
    const __hip_bfloat16* aSrc = A  + (size_t)(m0 + wid*16 + l4) * K + sswz;
    const __hip_bfloat16* bSrc = Bt + (size_t)(n0 + wid*16 + l4) * K + sswz;
    const int sOff = wid*1024 + lane*16;

    f32x4 acc[4][4] = {};
    const int wm = wid >> 1, wn = wid & 1;   // 4 m-waves x 2 n-waves
    const int cl = lane & 15, hi = lane >> 4;

    int aoff[4], boff[4];
#pragma unroll
    for (int m = 0; m < 4; ++m) {
        const int row = wm*64 + m*16 + cl;                 // 0..255
        aoff[m] = row*64 + ((hi ^ ((row >> 1) & 3)) << 4);
    }
#pragma unroll
    for (int n = 0; n < 4; ++n) {
        const int row = wn*64 + n*16 + cl;                 // 0..127
        boff[n] = row*64 + ((hi ^ ((row >> 1) & 3)) << 4);
    }

    auto STAGE = [&](char* aBuf, char* bBuf, int kt) {
        gload16(aSrc + kt,                  aBuf + sOff);
        gload16(aSrc + kt + (size_t)128*K,  aBuf + 8192 + sOff);
        gload16(bSrc + kt,                  bBuf + sOff);
    };

    const int NT = K >> 5;   // K/32
    STAGE(As0, Bs0, 0);
    STAGE(As1, Bs1, 32);

    for (int t = 0; t < NT; ++t) {
        if (t < NT - 1) asm volatile("s_waitcnt vmcnt(3)" ::: "memory");
        else            asm volatile("s_waitcnt vmcnt(0)" ::: "memory");
        __builtin_amdgcn_s_barrier();

        char* const ac = (t & 1) ? As1 : As0;
        char* const bc = (t & 1) ? Bs1 : Bs0;
        bf16x8 af[4], bfr[4];
#pragma unroll
        for (int m = 0; m < 4; ++m) af[m]  = *(const bf16x8*)(ac + aoff[m]);
#pragma unroll
        for (int n = 0; n < 4; ++n) bfr[n] = *(const bf16x8*)(bc + boff[n]);
        asm volatile("s_waitcnt lgkmcnt(0)" ::: "memory");
        __builtin_amdgcn_sched_barrier(0);
        __builtin_amdgcn_s_barrier();

        if (t + 2 < NT) STAGE(ac, bc, (t + 2) << 5);   // overwrite just-consumed buffer

        __builtin_amdgcn_s_setprio(1);
#pragma unroll
        for (int m = 0; m < 4; ++m)
#pragma unroll
            for (int n = 0; n < 4; ++n)
                acc[m][n] = __builtin_amdgcn_mfma_f32_16x16x32_bf16(af[m], bfr[n], acc[m][n], 0, 0, 0);
        __builtin_amdgcn_s_setprio(0);
    }

    const bool vpath = (EPI == 0) && (n0 >= 1536);

    if (!vpath) {
        // direct scalar stores
        const int strideN = (EPI == 0) ? 1536 : N;
#pragma unroll
        for (int n = 0; n < 4; ++n) {
            const int col = n0 + wn*64 + n*16 + cl;
            const float bv = bias[col];
#pragma unroll
            for (int m = 0; m < 4; ++m) {
#pragma unroll
                for (int i = 0; i < 4; ++i) {
                    const int row = m0 + wm*64 + m*16 + hi*4 + i;
                    float v = acc[m][n][i] + bv;
                    if constexpr (EPI == 1) {
                        const float y = 0.7978845608f * (v + 0.044715f*v*v*v);
                        const float e = __expf(-2.0f * fabsf(y));
                        const float th = (1.0f - e) / (1.0f + e);
                        v = 0.5f * v * (1.0f + copysignf(th, y));
                    }
                    outb[(size_t)row*strideN + col] = __float2bfloat16(v);
                }
            }
        }
    } else {
        // V -> V^T via LDS transpose, two 128-row halves (32 KB each, fits smem)
        const int hdbase = n0 - 1536;
        const int bb = m0 >> 10;
#pragma unroll
        for (int half = 0; half < 2; ++half) {
            __syncthreads();
            if ((wm >> 1) == half) {   // waves owning s-rows [half*128, half*128+128)
#pragma unroll
                for (int n = 0; n < 4; ++n) {
                    const int hdl = wn*64 + n*16 + cl;     // 0..127
                    const float bv = bias[n0 + hdl];
#pragma unroll
                    for (int m = 0; m < 4; ++m) {
                        const int sl = (wm & 1)*64 + m*16 + hi*4;   // s-local 0..127
                        ushort4 pk;
                        pk.x = f2bf_bits(acc[m][n][0] + bv);
                        pk.y = f2bf_bits(acc[m][n][1] + bv);
                        pk.z = f2bf_bits(acc[m][n][2] + bv);
                        pk.w = f2bf_bits(acc[m][n][3] + bv);
                        *(ushort4*)(smem + hdl*256 + ((((sl >> 3) ^ (hdl & 15))) << 4)
                                         + (sl & 7)*2) = pk;
                    }
                }
            }
            __syncthreads();
            const int hdl2 = tid >> 2;        // 0..127
            const int q4   = tid & 3;
            u16* dst = (u16*)outv + ((size_t)(bb*768) + hdbase + hdl2)*1024
                                  + (m0 & 1023) + half*128;
#pragma unroll
            for (int j = 0; j < 4; ++j) {
                const int ch = q4*4 + j;                  // 0..15
                const int slot = ch ^ (hdl2 & 15);
                *(float4*)((char*)dst + ch*16) = *(const float4*)(smem + hdl2*256 + (slot << 4));
            }
        }
    }
}

// ---------------- GEMM 64x128, 4 waves, counted-vmcnt dbuf: outf += A*Bt^T + bias ----
__global__ __launch_bounds__(256)
void gemm_res_kernel(const __hip_bfloat16* __restrict__ A,
                     const __hip_bfloat16* __restrict__ Bt,
                     const float* __restrict__ bias,
                     float* __restrict__ outf,
                     int N, int K, int nTiles)
{
    __shared__ __align__(16) char smem[49152];
    char* const As0 = smem;            // 8 KB [64][64]
    char* const As1 = smem + 8192;
    char* const Bs0 = smem + 16384;    // 16 KB [128][64]
    char* const Bs1 = smem + 32768;

    const int tid  = threadIdx.x;
    const int lane = tid & 63;
    const int wid  = tid >> 6;

    const int nwg   = gridDim.x;
    const int chunk = nwg >> 3;
    const int bid   = blockIdx.x;
    const int swz   = (bid & 7) * chunk + (bid >> 3);
    const int m0 = (swz / nTiles) * 64;
    const int n0 = (swz % nTiles) * 128;

    const int lrow = lane >> 3;                 // 0..7
    const int scol = ((lane & 7) ^ lrow) * 8;   // swizzled source col
    const __hip_bfloat16* aSrc = A  + (size_t)(m0 + wid*16 + lrow) * K + scol;
    const __hip_bfloat16* bSrc = Bt + (size_t)(n0 + wid*32 + lrow) * K + scol;
    const int aOff = wid*2048 + lane*16;
    const int bOff = wid*4096 + lane*16;

    f32x4 acc[2][4] = {};
    const int wm = wid >> 1, wn = wid & 1;
    const int cl = lane & 15, hi = lane >> 4;

    auto STAGE = [&](char* aBuf, char* bBuf, int kt) {
#pragma unroll
        for (int i = 0; i < 2; ++i)
            gload16(aSrc + kt + (size_t)i*8*K, aBuf + aOff + i*1024);
#pragma unroll
        for (int i = 0; i < 4; ++i)
            gload16(bSrc + kt + (size_t)i*8*K, bBuf + bOff + i*1024);
    };

    const int NT = K >> 6;   // K/64
    STAGE(As0, Bs0, 0);
    STAGE(As1, Bs1, 64);

    for (int t = 0; t < NT; ++t) {
        if (t < NT - 1) asm volatile("s_waitcnt vmcnt(6)" ::: "memory");
        else            asm volatile("s_waitcnt vmcnt(0)" ::: "memory");
        __builtin_amdgcn_s_barrier();

        char* const ac = (t & 1) ? As1 : As0;
        char* const bc = (t & 1) ? Bs1 : Bs0;
        bf16x8 af[2][2], bfr[2][4];
#pragma unroll
        for (int kk = 0; kk < 2; ++kk) {
#pragma unroll
            for (int m = 0; m < 2; ++m) {
                const int row  = wm*32 + m*16 + cl;
                const int slot = ((kk<<2) + hi) ^ (row & 7);
                af[kk][m] = *(const bf16x8*)(ac + row*128 + slot*16);
            }
#pragma unroll
            for (int n = 0; n < 4; ++n) {
                const int row  = wn*64 + n*16 + cl;
                const int slot = ((kk<<2) + hi) ^ (row & 7);
                bfr[kk][n] = *(const bf16x8*)(bc + row*128 + slot*16);
            }
        }
        asm volatile("s_waitcnt lgkmcnt(0)" ::: "memory");
        __builtin_amdgcn_sched_barrier(0);
        __builtin_amdgcn_s_barrier();

        if (t + 2 < NT) STAGE(ac, bc, (t + 2) << 6);

        __builtin_amdgcn_s_setprio(1);
#pragma unroll
        for (int kk = 0; kk < 2; ++kk)
#pragma unroll
            for (int m = 0; m < 2; ++m)
#pragma unroll
                for (int n = 0; n < 4; ++n)
                    acc[m][n] = __builtin_amdgcn_mfma_f32_16x16x32_bf16(af[kk][m], bfr[kk][n], acc[m][n], 0, 0, 0);
        __builtin_amdgcn_s_setprio(0);
    }

    __syncthreads();   // staging LDS dead; reuse for fp32 repack

#pragma unroll
    for (int n = 0; n < 4; ++n) {
        const int col = wn*64 + n*16 + cl;
        const float bv = bias[n0 + col];
#pragma unroll
        for (int m = 0; m < 2; ++m) {
#pragma unroll
            for (int i = 0; i < 4; ++i) {
                const int row = wm*32 + m*16 + hi*4 + i;
                *(float*)(smem + row*512 + ((((col >> 2) ^ (row & 31))) << 4)
                               + ((col & 3) << 2)) = acc[m][n][i] + bv;
            }
        }
    }
    __syncthreads();
    const int r = tid >> 2;
    const int part = tid & 3;
    float* drow = outf + (size_t)(m0 + r) * N + n0;
#pragma unroll
    for (int j = 0; j < 8; ++j) {
        const int ch = part + j*4;
        f32x4 vv = *(const f32x4*)(smem + r*512 + ((ch ^ (r & 31)) << 4));
        float* dp = drow + ch*4;
        f32x4 g = *(const f32x4*)dp;
        g += vv;
        *(f32x4*)dp = g;
    }
}

// ---------------- flash attention, MFMA bf16, 8 waves / 128 q-rows ----------------
__global__ __launch_bounds__(512)
void attn_kernel(const __hip_bfloat16* __restrict__ qkb, const __hip_bfloat16* __restrict__ vtb,
                 __hip_bfloat16* __restrict__ attno)
{
    __shared__ __align__(16) char Ks[2][8192];  // [t 64][d 64] bf16, slot^=(t&7)
    __shared__ __align__(16) char Vs[2][8192];  // [d 64][t 64] bf16, slot^=(d&7)
    __shared__ __align__(16) char Ps[16384];    // per-wave P: [q 16][t 64], slot^=(q&7)

    const u16* qk = (const u16*)qkb;
    const u16* vt = (const u16*)vtb;
    const int nwg = gridDim.x, bid = blockIdx.x, chunk = nwg >> 3;
    const int swz = (bid & 7) * chunk + (bid >> 3);
    const int bh = swz >> 3, qb = swz & 7;
    const int b = bh / H_, h = bh % H_;
    const int tid = threadIdx.x;
    const int lane = tid & 63, wid = tid >> 6;   // wid 0..7
    const int cl = lane & 15, hi = lane >> 4;
    const size_t browq = (size_t)(b*S_ + qb*128);

    bf16x8 qf[2];
    {
        const u16* qp = qk + (browq + wid*16 + cl)*1536 + h*64;
        qf[0] = *(const bf16x8*)(qp + hi*8);
        qf[1] = *(const bf16x8*)(qp + 32 + hi*8);
    }

    const int lrow = lane >> 3;                  // 0..7
    const int scol = ((lane & 7) ^ lrow) * 8;    // swizzled source col
    const u16* kbase = qk + ((size_t)b*S_ + wid*8 + lrow)*1536 + 768 + h*64 + scol;
    const u16* vbase = vt + (((size_t)(b*H_ + h))*64 + wid*8 + lrow)*1024 + scol;
    const int ldst = wid*1024 + lane*16;

    f32x4 acc_o[4] = {};
    float m_run = -1e30f;
    float l_part[4] = {0.f, 0.f, 0.f, 0.f};
    char* pbase = Ps + wid*2048;

    {
        gload16(kbase, Ks[0] + ldst);
        gload16(vbase, Vs[0] + ldst);
    }

    for (int t = 0; t < 16; ++t) {
        __syncthreads();
        if (t < 15) {
            const int nb = (t+1) & 1;
            gload16(kbase + (size_t)(t+1)*64*1536, Ks[nb] + ldst);
            gload16(vbase + (t+1)*64,              Vs[nb] + ldst);
        }
        const char* ks = Ks[t & 1];
        const char* vs = Vs[t & 1];

        f32x4 sc[4] = {};
#pragma unroll
        for (int kk = 0; kk < 2; ++kk) {
            bf16x8 kf[4];
#pragma unroll
            for (int n = 0; n < 4; ++n) {
                const int row = n*16 + cl;
                kf[n] = *(const bf16x8*)(ks + row*128 + (((kk*4 + hi) ^ (cl & 7)) << 4));
            }
#pragma unroll
            for (int n = 0; n < 4; ++n)
                sc[n] = __builtin_amdgcn_mfma_f32_16x16x32_bf16(qf[kk], kf[n], sc[n], 0, 0, 0);
        }

#pragma unroll
        for (int n = 0; n < 4; ++n)
#pragma unroll
            for (int i = 0; i < 4; ++i)
                sc[n][i] *= 0.125f;

        float gmax = sc[0][0];
#pragma unroll
        for (int n = 0; n < 4; ++n)
#pragma unroll
            for (int i = 0; i < 4; ++i)
                gmax = fmaxf(gmax, sc[n][i]);
        gmax = fmaxf(gmax, __shfl_xor(gmax, 1));
        gmax = fmaxf(gmax, __shfl_xor(gmax, 2));
        gmax = fmaxf(gmax, __shfl_xor(gmax, 4));
        gmax = fmaxf(gmax, __shfl_xor(gmax, 8));
        if (gmax > m_run + 4.0f) {
            const float corr = __expf(m_run - gmax);
            m_run = gmax;
#pragma unroll
            for (int i = 0; i < 4; ++i) l_part[i] *= corr;
#pragma unroll
            for (int nd = 0; nd < 4; ++nd)
#pragma unroll
                for (int i = 0; i < 4; ++i)
                    acc_o[nd][i] *= corr;
        }

#pragma unroll
        for (int n = 0; n < 4; ++n) {
#pragma unroll
            for (int i = 0; i < 4; ++i) {
                const float e = __expf(sc[n][i] - m_run);
                l_part[i] += e;
                const int q = hi*4 + i;
                const int slot = (n*2 + (cl >> 3)) ^ (q & 7);
                *(u16*)(pbase + q*128 + slot*16 + (cl & 7)*2) = f2bf_bits(e);
            }
        }

        asm volatile("s_waitcnt lgkmcnt(0)" ::: "memory");
        __builtin_amdgcn_sched_barrier(0);

#pragma unroll
        for (int kk = 0; kk < 2; ++kk) {
            const bf16x8 pf = *(const bf16x8*)(pbase + cl*128 + (((kk*4 + hi) ^ (cl & 7)) << 4));
            bf16x8 vf[4];
#pragma unroll
            for (int nd = 0; nd < 4; ++nd) {
                const int d = nd*16 + cl;
                vf[nd] = *(const bf16x8*)(vs + d*128 + (((kk*4 + hi) ^ (d & 7)) << 4));
            }
#pragma unroll
            for (int nd = 0; nd < 4; ++nd)
                acc_o[nd] = __builtin_amdgcn_mfma_f32_16x16x32_bf16(pf, vf[nd], acc_o[nd], 0, 0, 0);
        }
    }

    u16* op = (u16*)attno;
#pragma unroll
    for (int i = 0; i < 4; ++i) {
        float l = l_part[i];
        l += __shfl_xor(l, 1);
        l += __shfl_xor(l, 2);
        l += __shfl_xor(l, 4);
        l += __shfl_xor(l, 8);
        const float inv = 1.f / l;
        const size_t row = browq + wid*16 + hi*4 + i;
#pragma unroll
        for (int nd = 0; nd < 4; ++nd)
            op[row*768 + h*64 + nd*16 + cl] = f2bf_bits(acc_o[nd][i] * inv);
    }
}

// ---------------- classifier ----------------
__global__ __launch_bounds__(256)
void cls_kernel(const float* __restrict__ x, const float* __restrict__ Wc,
                const float* __restrict__ bc, float* __restrict__ out)
{
    const int b = blockIdx.x;
    const float* xr = x + (size_t)b * S_ * D_;
    float a0 = 0.f, a1 = 0.f;
    for (int d = threadIdx.x; d < 768; d += 256) {
        float xv = xr[d];
        a0 += xv * Wc[d*2+0];
        a1 += xv * Wc[d*2+1];
    }
#pragma unroll
    for (int off = 32; off > 0; off >>= 1) { a0 += __shfl_xor(a0, off); a1 += __shfl_xor(a1, off); }
    __shared__ float r0[4], r1[4];
    const int w = threadIdx.x >> 6;
    if ((threadIdx.x & 63) == 0) { r0[w] = a0; r1[w] = a1; }
    __syncthreads();
    if (threadIdx.x == 0) {
        out[b*2+0] = r0[0]+r0[1]+r0[2]+r0[3] + bc[0];
        out[b*2+1] = r1[0]+r1[1]+r1[2]+r1[3] + bc[1];
    }
}

// ---------------- launch ----------------
extern "C" void kernel_launch(void* const* d_in, const int* in_sizes, int n_in,
                              void* d_out, int out_size, void* d_ws, size_t ws_size,
                              hipStream_t stream)
{
    const int*   tokens  = (const int*)  d_in[0];
    const float* tok_emb = (const float*)d_in[1];
    const float* pos_emb = (const float*)d_in[2];
    const float* e_s     = (const float*)d_in[3];
    const float* e_b     = (const float*)d_in[4];
    const float* Wq      = (const float*)d_in[5];
    const float* bq      = (const float*)d_in[6];
    const float* Wk      = (const float*)d_in[7];
    const float* bk      = (const float*)d_in[8];
    const float* Wv      = (const float*)d_in[9];
    const float* bv      = (const float*)d_in[10];
    const float* Wo      = (const float*)d_in[11];
    const float* bo      = (const float*)d_in[12];
    const float* l1s     = (const float*)d_in[13];
    const float* l1b     = (const float*)d_in[14];
    const float* l2s     = (const float*)d_in[15];
    const float* l2b     = (const float*)d_in[16];
    const float* W1      = (const float*)d_in[17];
    const float* b1      = (const float*)d_in[18];
    const float* W2      = (const float*)d_in[19];
    const float* b2      = (const float*)d_in[20];
    const float* Wc      = (const float*)d_in[21];
    const float* bc      = (const float*)d_in[22];
    (void)in_sizes; (void)n_in; (void)out_size;

    if (ws_size < 102346752) return;   // need ~102.4 MB

    char* ws = (char*)d_ws;
    __hip_bfloat16* wbuf = (__hip_bfloat16*)(ws + 0);          // 14,155,776 B
    float*          bqkv = (float*)(ws + 14155776);            //    110,592 B
    float*          x    = (float*)(ws + 14266368);            // 25,165,824 B
    __hip_bfloat16* xn   = (__hip_bfloat16*)(ws + 39432192);   // 12,582,912 B
    __hip_bfloat16* qk   = (__hip_bfloat16*)(ws + 52015104);   // 25,165,824 B [8192][1536]
    __hip_bfloat16* vT   = (__hip_bfloat16*)(ws + 77180928);   // 12,582,912 B [b*768+hd][1024]
    __hip_bfloat16* att  = (__hip_bfloat16*)(ws + 89763840);   // 12,582,912 B (end 102,346,752)
    __hip_bfloat16* hbuf = qk;                                 // aliases qk+vT+att (50,331,648 B)

    __hip_bfloat16* wqkv_t = wbuf;
    __hip_bfloat16* wo_t   = wbuf + 1769472;
    __hip_bfloat16* w1_t   = wbuf + 2359296;
    __hip_bfloat16* w2_t   = wbuf + 4718592;

    prep_bqkv_kernel<<<108, 256, 0, stream>>>(bq, bk, bv, bqkv);
    embed_ln_kernel<<<2048, 256, 0, stream>>>(tokens, tok_emb, pos_emb, e_s, e_b, x);

    for (int l = 0; l < L_; ++l) {
        prep_layer_kernel<<<1728, 256, 0, stream>>>(Wq, Wk, Wv, Wo, W1, W2, l, wbuf);
        ln_kernel<<<2048, 256, 0, stream>>>(x, l1s + l*768, l1b + l*768, xn);
        gemm256_kernel<0><<<576, 512, 0, stream>>>(xn, wqkv_t, bqkv + l*2304, qk, vT, 2304, 768, 18);
        attn_kernel<<<768, 512, 0, stream>>>(qk, vT, att);
        gemm_res_kernel<<<768, 256, 0, stream>>>(att, wo_t, bo + l*768, x, 768, 768, 6);
        ln_kernel<<<2048, 256, 0, stream>>>(x, l2s + l*768, l2b + l*768, xn);
        gemm256_kernel<1><<<768, 512, 0, stream>>>(xn, w1_t, b1 + l*3072, hbuf, nullptr, 3072, 768, 24);
        gemm_res_kernel<<<768, 256, 0, stream>>>(hbuf, w2_t, b2 + l*768, x, 768, 3072, 6);
    }
    cls_kernel<<<8, 256, 0, stream>>>(x, Wc, bc, (float*)d_out);
}